// Round 1
// baseline (6302.403 us; speedup 1.0000x reference)
//
#include <hip/hip_runtime.h>

#define IN_C  256
#define HID_C 128
#define OUT_C 2

__device__ __forceinline__ void atomAddF(float* p, float v) {
    // HW global_atomic_add_f32 (avoids CAS loop under default compile flags)
    unsafeAtomicAdd(p, v);
}

// ---- degree / norm ---------------------------------------------------------
__global__ void k_deg_init(float* __restrict__ deg, int n) {
    int i = blockIdx.x * 256 + threadIdx.x;
    if (i < n) deg[i] = 1.0f;                 // self-loop weight
}

__global__ void k_deg_scatter(const int* __restrict__ ei, const float* __restrict__ w,
                              float* __restrict__ deg, int E) {
    int e = blockIdx.x * 256 + threadIdx.x;
    if (e < E) atomAddF(&deg[ei[E + e]], w[e]);
}

__global__ void k_dinv(float* __restrict__ deg, int n) {
    int i = blockIdx.x * 256 + threadIdx.x;
    if (i < n) { float d = deg[i]; deg[i] = d > 0.f ? rsqrtf(d) : 0.f; }
}

__global__ void k_norm(const int* __restrict__ ei, const float* __restrict__ w,
                       const float* __restrict__ dinv, float* __restrict__ norm, int E) {
    int e = blockIdx.x * 256 + threadIdx.x;
    if (e < E) norm[e] = dinv[ei[e]] * w[e] * dinv[ei[E + e]];
}

// ---- GEMM1: h1[N,128] = x[N,256] @ W1[256,128] -----------------------------
__global__ __launch_bounds__(256) void k_gemm1(const float* __restrict__ x,
                                               const float* __restrict__ W1,
                                               float* __restrict__ h1, int n) {
    __shared__ float xs[16][260];             // +4 pad: float4-aligned, bank-clean
    int row0 = blockIdx.x * 16;
    {
        const float4* xsrc = (const float4*)(x + (size_t)row0 * IN_C);
        for (int i = threadIdx.x; i < 16 * 64; i += 256) {
            int r = i >> 6, c = i & 63;
            if (row0 + r < n)
                *((float4*)&xs[r][c * 4]) = xsrc[(size_t)r * 64 + c];
        }
    }
    __syncthreads();
    int r  = threadIdx.x >> 4;                // 16 rows
    int cg = (threadIdx.x & 15) * 8;          // 16 col-groups of 8
    if (row0 + r >= n) return;
    float acc[8];
#pragma unroll
    for (int j = 0; j < 8; j++) acc[j] = 0.f;
    const float* wp = W1 + cg;
#pragma unroll 4
    for (int k = 0; k < IN_C; k++) {
        float xv = xs[r][k];
        float4 a = *((const float4*)(wp + k * HID_C));
        float4 b = *((const float4*)(wp + k * HID_C + 4));
        acc[0] = fmaf(xv, a.x, acc[0]);
        acc[1] = fmaf(xv, a.y, acc[1]);
        acc[2] = fmaf(xv, a.z, acc[2]);
        acc[3] = fmaf(xv, a.w, acc[3]);
        acc[4] = fmaf(xv, b.x, acc[4]);
        acc[5] = fmaf(xv, b.y, acc[5]);
        acc[6] = fmaf(xv, b.z, acc[6]);
        acc[7] = fmaf(xv, b.w, acc[7]);
    }
    float4* o = (float4*)(h1 + (size_t)(row0 + r) * HID_C + cg);
    o[0] = make_float4(acc[0], acc[1], acc[2], acc[3]);
    o[1] = make_float4(acc[4], acc[5], acc[6], acc[7]);
}

// ---- layer-1 aggregation ---------------------------------------------------
// init: agg1[n,c] = b1[c] + dinv[n]^2 * h1[n,c]   (self-loop + bias, overwrites poison)
__global__ void k_init1(const float* __restrict__ h1, const float* __restrict__ dinv,
                        const float* __restrict__ b1, float* __restrict__ agg1, int n) {
    int i = blockIdx.x * 256 + threadIdx.x;   // one float4 per thread
    if (i >= n * (HID_C / 4)) return;
    int node = i >> 5, c4 = i & 31;
    float di = dinv[node]; float sc = di * di;
    float4 h = ((const float4*)h1)[i];
    float4 b = ((const float4*)b1)[c4];
    ((float4*)agg1)[i] = make_float4(b.x + sc * h.x, b.y + sc * h.y,
                                     b.z + sc * h.z, b.w + sc * h.w);
}

__global__ __launch_bounds__(256) void k_scatter1(const int* __restrict__ ei,
                                                  const float* __restrict__ norm,
                                                  const float* __restrict__ h1,
                                                  float* __restrict__ agg1, int E) {
    int gid = blockIdx.x * 256 + threadIdx.x; // 32 threads per edge (float4 each)
    int e = gid >> 5;
    if (e >= E) return;
    int c4 = gid & 31;
    int s = ei[e], d = ei[E + e];
    float nm = norm[e];
    float4 v = ((const float4*)(h1 + (size_t)s * HID_C))[c4];
    float* dp = agg1 + (size_t)d * HID_C + c4 * 4;
    atomAddF(dp + 0, nm * v.x);
    atomAddF(dp + 1, nm * v.y);
    atomAddF(dp + 2, nm * v.z);
    atomAddF(dp + 3, nm * v.w);
}

// ---- GEMM2: h2[N,2] = relu(agg1) @ W2[128,2] -------------------------------
__global__ __launch_bounds__(256) void k_gemm2(const float* __restrict__ agg1,
                                               const float* __restrict__ W2,
                                               float* __restrict__ h2, int n) {
    int lane = threadIdx.x & 63;
    int wave = threadIdx.x >> 6;
    int node = blockIdx.x * 8 + wave * 2 + (lane >> 5);
    int l = lane & 31;
    float s0 = 0.f, s1 = 0.f;
    if (node < n) {
        float4 v = ((const float4*)(agg1 + (size_t)node * HID_C))[l];
        v.x = fmaxf(v.x, 0.f); v.y = fmaxf(v.y, 0.f);
        v.z = fmaxf(v.z, 0.f); v.w = fmaxf(v.w, 0.f);
        const float2* w2 = (const float2*)W2;
        float2 w0 = w2[l * 4 + 0], w1 = w2[l * 4 + 1];
        float2 wq = w2[l * 4 + 2], w3 = w2[l * 4 + 3];
        s0 = v.x * w0.x + v.y * w1.x + v.z * wq.x + v.w * w3.x;
        s1 = v.x * w0.y + v.y * w1.y + v.z * wq.y + v.w * w3.y;
    }
#pragma unroll
    for (int d = 16; d > 0; d >>= 1) {
        s0 += __shfl_down(s0, d, 32);
        s1 += __shfl_down(s1, d, 32);
    }
    if (node < n && l == 0)
        ((float2*)h2)[node] = make_float2(s0, s1);
}

// ---- layer-2 aggregation ---------------------------------------------------
__global__ void k_init2(const float* __restrict__ h2, const float* __restrict__ dinv,
                        const float* __restrict__ b2, float* __restrict__ out, int n) {
    int i = blockIdx.x * 256 + threadIdx.x;
    if (i >= n) return;
    float di = dinv[i]; float sc = di * di;
    float2 h = ((const float2*)h2)[i];
    ((float2*)out)[i] = make_float2(b2[0] + sc * h.x, b2[1] + sc * h.y);
}

__global__ void k_scatter2(const int* __restrict__ ei, const float* __restrict__ norm,
                           const float* __restrict__ h2, float* __restrict__ out, int E) {
    int e = blockIdx.x * 256 + threadIdx.x;
    if (e >= E) return;
    int s = ei[e], d = ei[E + e];
    float nm = norm[e];
    float2 v = ((const float2*)h2)[s];
    atomAddF(&out[(size_t)d * 2 + 0], nm * v.x);
    atomAddF(&out[(size_t)d * 2 + 1], nm * v.y);
}

extern "C" void kernel_launch(void* const* d_in, const int* in_sizes, int n_in,
                              void* d_out, int out_size, void* d_ws, size_t ws_size,
                              hipStream_t stream) {
    const float* x  = (const float*)d_in[0];
    const int*   ei = (const int*)d_in[1];   // [2,E] int32: src = ei[0:E], dst = ei[E:2E]
    const float* ew = (const float*)d_in[2];
    const float* W1 = (const float*)d_in[3];
    const float* b1 = (const float*)d_in[4];
    const float* W2 = (const float*)d_in[5];
    const float* b2 = (const float*)d_in[6];
    float* out = (float*)d_out;

    int N = in_sizes[0] / IN_C;
    int E = in_sizes[2];

    char* ws = (char*)d_ws;
    float* dinv = (float*)ws; ws += (size_t)N * 4;            // deg, then dinv in place
    float* norm = (float*)ws; ws += (size_t)E * 4;
    float* h1   = (float*)ws; ws += (size_t)N * HID_C * 4;
    float* agg1 = (float*)ws; ws += (size_t)N * HID_C * 4;
    float* h2   = (float*)ws; ws += (size_t)N * OUT_C * 4;

    int nb_n = (N + 255) / 256;
    int nb_e = (E + 255) / 256;

    k_deg_init   <<<nb_n, 256, 0, stream>>>(dinv, N);
    k_deg_scatter<<<nb_e, 256, 0, stream>>>(ei, ew, dinv, E);
    k_dinv       <<<nb_n, 256, 0, stream>>>(dinv, N);
    k_norm       <<<nb_e, 256, 0, stream>>>(ei, ew, dinv, norm, E);
    k_gemm1      <<<(N + 15) / 16, 256, 0, stream>>>(x, W1, h1, N);
    k_init1      <<<(N * (HID_C / 4) + 255) / 256, 256, 0, stream>>>(h1, dinv, b1, agg1, N);
    k_scatter1   <<<(int)(((size_t)E * 32 + 255) / 256), 256, 0, stream>>>(ei, norm, h1, agg1, E);
    k_gemm2      <<<(N + 7) / 8, 256, 0, stream>>>(agg1, W2, h2, N);
    k_init2      <<<nb_n, 256, 0, stream>>>(h2, dinv, b2, out, N);
    k_scatter2   <<<nb_e, 256, 0, stream>>>(ei, norm, h2, out, E);
}

// Round 2
// 1259.303 us; speedup vs baseline: 5.0047x; 5.0047x over previous
//
#include <hip/hip_runtime.h>

#define IN_C  256
#define HID_C 128
#define OUT_C 2

__device__ __forceinline__ void atomAddF(float* p, float v) {
    unsafeAtomicAdd(p, v);   // HW global_atomic_add_f32
}

// ---- degree + histogram ----------------------------------------------------
__global__ void k_deg_init(float* __restrict__ deg, int* __restrict__ cnt, int n) {
    int i = blockIdx.x * 256 + threadIdx.x;
    if (i < n) { deg[i] = 1.0f; cnt[i] = 0; }   // self-loop weight, zero hist
}

__global__ void k_deg_hist(const int* __restrict__ ei, const float* __restrict__ w,
                           float* __restrict__ deg, int* __restrict__ cnt, int E) {
    int e = blockIdx.x * 256 + threadIdx.x;
    if (e < E) {
        int d = ei[E + e];
        atomAddF(&deg[d], w[e]);
        atomicAdd(&cnt[d], 1);
    }
}

__global__ void k_dinv(float* __restrict__ deg, int n) {
    int i = blockIdx.x * 256 + threadIdx.x;
    if (i < n) { float d = deg[i]; deg[i] = d > 0.f ? rsqrtf(d) : 0.f; }
}

// ---- exclusive scan of cnt -> rowptr (1024 elems / block) ------------------
__global__ __launch_bounds__(256) void k_scanA(const int* __restrict__ cnt,
                                               int* __restrict__ excl,
                                               int* __restrict__ bsum, int n) {
    __shared__ int ss[256];
    int t = threadIdx.x;
    int base = blockIdx.x * 1024 + t * 4;
    int v0 = 0, v1 = 0, v2 = 0, v3 = 0;
    if (base + 0 < n) v0 = cnt[base + 0];
    if (base + 1 < n) v1 = cnt[base + 1];
    if (base + 2 < n) v2 = cnt[base + 2];
    if (base + 3 < n) v3 = cnt[base + 3];
    ss[t] = v0 + v1 + v2 + v3;
    __syncthreads();
    for (int d = 1; d < 256; d <<= 1) {
        int x = (t >= d) ? ss[t - d] : 0;
        __syncthreads();
        ss[t] += x;
        __syncthreads();
    }
    int pre = (t == 0) ? 0 : ss[t - 1];
    if (t == 255) bsum[blockIdx.x] = ss[255];
    if (base + 0 < n) excl[base + 0] = pre;
    if (base + 1 < n) excl[base + 1] = pre + v0;
    if (base + 2 < n) excl[base + 2] = pre + v0 + v1;
    if (base + 3 < n) excl[base + 3] = pre + v0 + v1 + v2;
}

__global__ __launch_bounds__(256) void k_scanB(int* __restrict__ bsum, int nb) {
    __shared__ int ss[256];
    int t = threadIdx.x;
    int v = (t < nb) ? bsum[t] : 0;
    ss[t] = v;
    __syncthreads();
    for (int d = 1; d < 256; d <<= 1) {
        int x = (t >= d) ? ss[t - d] : 0;
        __syncthreads();
        ss[t] += x;
        __syncthreads();
    }
    if (t < nb) bsum[t] = ss[t] - v;   // exclusive
}

__global__ void k_scanC(int* __restrict__ rowptr, int* __restrict__ cursor,
                        const int* __restrict__ bsum, int n, int E) {
    int i = blockIdx.x * 256 + threadIdx.x;
    if (i < n) {
        int v = rowptr[i] + bsum[i >> 10];
        rowptr[i] = v;
        cursor[i] = v;
    }
    if (i == 0) rowptr[n] = E;
}

// ---- bucket scatter: edata[pos] = {src, norm} sorted by dst ---------------
__global__ void k_build(const int* __restrict__ ei, const float* __restrict__ w,
                        const float* __restrict__ dinv, int* __restrict__ cursor,
                        int2* __restrict__ edata, int E) {
    int e = blockIdx.x * 256 + threadIdx.x;
    if (e >= E) return;
    int s = ei[e], d = ei[E + e];
    float nm = dinv[s] * w[e] * dinv[d];
    int pos = atomicAdd(&cursor[d], 1);
    edata[pos] = make_int2(s, __float_as_int(nm));
}

// ---- GEMM1: h1[N,128] = x[N,256] @ W1[256,128] -----------------------------
__global__ __launch_bounds__(256) void k_gemm1(const float* __restrict__ x,
                                               const float* __restrict__ W1,
                                               float* __restrict__ h1, int n) {
    __shared__ float xs[16][260];
    int row0 = blockIdx.x * 16;
    {
        const float4* xsrc = (const float4*)(x + (size_t)row0 * IN_C);
        for (int i = threadIdx.x; i < 16 * 64; i += 256) {
            int r = i >> 6, c = i & 63;
            if (row0 + r < n)
                *((float4*)&xs[r][c * 4]) = xsrc[(size_t)r * 64 + c];
        }
    }
    __syncthreads();
    int r  = threadIdx.x >> 4;
    int cg = (threadIdx.x & 15) * 8;
    if (row0 + r >= n) return;
    float acc[8];
#pragma unroll
    for (int j = 0; j < 8; j++) acc[j] = 0.f;
    const float* wp = W1 + cg;
#pragma unroll 4
    for (int k = 0; k < IN_C; k++) {
        float xv = xs[r][k];
        float4 a = *((const float4*)(wp + k * HID_C));
        float4 b = *((const float4*)(wp + k * HID_C + 4));
        acc[0] = fmaf(xv, a.x, acc[0]);
        acc[1] = fmaf(xv, a.y, acc[1]);
        acc[2] = fmaf(xv, a.z, acc[2]);
        acc[3] = fmaf(xv, a.w, acc[3]);
        acc[4] = fmaf(xv, b.x, acc[4]);
        acc[5] = fmaf(xv, b.y, acc[5]);
        acc[6] = fmaf(xv, b.z, acc[6]);
        acc[7] = fmaf(xv, b.w, acc[7]);
    }
    float4* o = (float4*)(h1 + (size_t)(row0 + r) * HID_C + cg);
    o[0] = make_float4(acc[0], acc[1], acc[2], acc[3]);
    o[1] = make_float4(acc[4], acc[5], acc[6], acc[7]);
}

// ---- layer-1 aggregation: one wave per dst node, no atomics ---------------
__global__ __launch_bounds__(256) void k_agg1(const int* __restrict__ rowptr,
                                              const int2* __restrict__ edata,
                                              const float* __restrict__ h1,
                                              const float* __restrict__ dinv,
                                              const float* __restrict__ b1,
                                              float* __restrict__ agg1, int n) {
    int wid  = (blockIdx.x * 256 + threadIdx.x) >> 6;   // node id
    int lane = threadIdx.x & 63;                        // owns cols 2*lane, 2*lane+1
    if (wid >= n) return;
    int beg = rowptr[wid], end = rowptr[wid + 1];
    float2 acc = make_float2(0.f, 0.f);
    int j = beg;
    for (; j + 4 <= end; j += 4) {            // 4-deep ILP on the gather
        int2 e0 = edata[j + 0], e1 = edata[j + 1];
        int2 e2 = edata[j + 2], e3 = edata[j + 3];
        float2 v0 = ((const float2*)(h1 + (size_t)e0.x * HID_C))[lane];
        float2 v1 = ((const float2*)(h1 + (size_t)e1.x * HID_C))[lane];
        float2 v2 = ((const float2*)(h1 + (size_t)e2.x * HID_C))[lane];
        float2 v3 = ((const float2*)(h1 + (size_t)e3.x * HID_C))[lane];
        float n0 = __int_as_float(e0.y), n1 = __int_as_float(e1.y);
        float n2 = __int_as_float(e2.y), n3 = __int_as_float(e3.y);
        acc.x = fmaf(n0, v0.x, acc.x); acc.y = fmaf(n0, v0.y, acc.y);
        acc.x = fmaf(n1, v1.x, acc.x); acc.y = fmaf(n1, v1.y, acc.y);
        acc.x = fmaf(n2, v2.x, acc.x); acc.y = fmaf(n2, v2.y, acc.y);
        acc.x = fmaf(n3, v3.x, acc.x); acc.y = fmaf(n3, v3.y, acc.y);
    }
    for (; j < end; j++) {
        int2 e0 = edata[j];
        float2 v0 = ((const float2*)(h1 + (size_t)e0.x * HID_C))[lane];
        float n0 = __int_as_float(e0.y);
        acc.x = fmaf(n0, v0.x, acc.x); acc.y = fmaf(n0, v0.y, acc.y);
    }
    float di = dinv[wid]; float sc = di * di;           // self-loop norm
    float2 hv = ((const float2*)(h1 + (size_t)wid * HID_C))[lane];
    float2 bv = ((const float2*)b1)[lane];
    acc.x += bv.x + sc * hv.x;
    acc.y += bv.y + sc * hv.y;
    ((float2*)(agg1 + (size_t)wid * HID_C))[lane] = acc;
}

// ---- GEMM2: h2[N,2] = relu(agg1) @ W2[128,2] -------------------------------
__global__ __launch_bounds__(256) void k_gemm2(const float* __restrict__ agg1,
                                               const float* __restrict__ W2,
                                               float* __restrict__ h2, int n) {
    int lane = threadIdx.x & 63;
    int wave = threadIdx.x >> 6;
    int node = blockIdx.x * 8 + wave * 2 + (lane >> 5);
    int l = lane & 31;
    float s0 = 0.f, s1 = 0.f;
    if (node < n) {
        float4 v = ((const float4*)(agg1 + (size_t)node * HID_C))[l];
        v.x = fmaxf(v.x, 0.f); v.y = fmaxf(v.y, 0.f);
        v.z = fmaxf(v.z, 0.f); v.w = fmaxf(v.w, 0.f);
        const float2* w2 = (const float2*)W2;
        float2 w0 = w2[l * 4 + 0], w1 = w2[l * 4 + 1];
        float2 wq = w2[l * 4 + 2], w3 = w2[l * 4 + 3];
        s0 = v.x * w0.x + v.y * w1.x + v.z * wq.x + v.w * w3.x;
        s1 = v.x * w0.y + v.y * w1.y + v.z * wq.y + v.w * w3.y;
    }
#pragma unroll
    for (int d = 16; d > 0; d >>= 1) {
        s0 += __shfl_down(s0, d, 32);
        s1 += __shfl_down(s1, d, 32);
    }
    if (node < n && l == 0)
        ((float2*)h2)[node] = make_float2(s0, s1);
}

// ---- layer-2 aggregation: wave per node, lanes over edges ------------------
__global__ __launch_bounds__(256) void k_agg2(const int* __restrict__ rowptr,
                                              const int2* __restrict__ edata,
                                              const float* __restrict__ h2,
                                              const float* __restrict__ dinv,
                                              const float* __restrict__ b2,
                                              float* __restrict__ out, int n) {
    int wid  = (blockIdx.x * 256 + threadIdx.x) >> 6;
    int lane = threadIdx.x & 63;
    if (wid >= n) return;
    int beg = rowptr[wid], end = rowptr[wid + 1];
    float sx = 0.f, sy = 0.f;
    for (int j = beg + lane; j < end; j += 64) {
        int2 ed = edata[j];
        float nm = __int_as_float(ed.y);
        float2 v = ((const float2*)h2)[ed.x];
        sx = fmaf(nm, v.x, sx);
        sy = fmaf(nm, v.y, sy);
    }
#pragma unroll
    for (int d = 32; d > 0; d >>= 1) {
        sx += __shfl_xor(sx, d);
        sy += __shfl_xor(sy, d);
    }
    if (lane == 0) {
        float di = dinv[wid]; float sc = di * di;
        float2 hv = ((const float2*)h2)[wid];
        ((float2*)out)[wid] = make_float2(b2[0] + sc * hv.x + sx,
                                          b2[1] + sc * hv.y + sy);
    }
}

extern "C" void kernel_launch(void* const* d_in, const int* in_sizes, int n_in,
                              void* d_out, int out_size, void* d_ws, size_t ws_size,
                              hipStream_t stream) {
    const float* x  = (const float*)d_in[0];
    const int*   ei = (const int*)d_in[1];   // [2,E] int32: src = ei[0:E], dst = ei[E:2E]
    const float* ew = (const float*)d_in[2];
    const float* W1 = (const float*)d_in[3];
    const float* b1 = (const float*)d_in[4];
    const float* W2 = (const float*)d_in[5];
    const float* b2 = (const float*)d_in[6];
    float* out = (float*)d_out;

    int N = in_sizes[0] / IN_C;
    int E = in_sizes[2];

    char* ws = (char*)d_ws;
    float* dinv   = (float*)ws; ws += (size_t)N * 4;
    int*   cnt    = (int*)ws;   ws += (size_t)N * 4;
    int*   rowptr = (int*)ws;   ws += (size_t)(N + 1) * 4 + 4;   // keep 8B align
    int*   cursor = (int*)ws;   ws += (size_t)N * 4;
    int*   bsum   = (int*)ws;   ws += 1024;
    int2*  edata  = (int2*)ws;  ws += (size_t)E * 8;
    float* h1     = (float*)ws; ws += (size_t)N * HID_C * 4;
    float* agg1   = (float*)ws; ws += (size_t)N * HID_C * 4;
    float* h2     = (float*)ws; ws += (size_t)N * OUT_C * 4;

    int nb_n = (N + 255) / 256;
    int nb_e = (E + 255) / 256;
    int nb_s = (N + 1023) / 1024;            // scan blocks (<= 256 supported)
    int nb_w = (N * 64 + 255) / 256;         // wave-per-node grids

    k_deg_init<<<nb_n, 256, 0, stream>>>(dinv, cnt, N);
    k_deg_hist<<<nb_e, 256, 0, stream>>>(ei, ew, dinv, cnt, E);
    k_dinv    <<<nb_n, 256, 0, stream>>>(dinv, N);
    k_scanA   <<<nb_s, 256, 0, stream>>>(cnt, rowptr, bsum, N);
    k_scanB   <<<1,    256, 0, stream>>>(bsum, nb_s);
    k_scanC   <<<nb_n, 256, 0, stream>>>(rowptr, cursor, bsum, N, E);
    k_build   <<<nb_e, 256, 0, stream>>>(ei, ew, dinv, cursor, edata, E);
    k_gemm1   <<<(N + 15) / 16, 256, 0, stream>>>(x, W1, h1, N);
    k_agg1    <<<nb_w, 256, 0, stream>>>(rowptr, edata, h1, dinv, b1, agg1, N);
    k_gemm2   <<<(N + 7) / 8, 256, 0, stream>>>(agg1, W2, h2, N);
    k_agg2    <<<nb_w, 256, 0, stream>>>(rowptr, edata, h2, dinv, b2, out, N);
}

// Round 3
// 979.368 us; speedup vs baseline: 6.4352x; 1.2858x over previous
//
#include <hip/hip_runtime.h>

#define IN_C  256
#define HID_C 128
#define OUT_C 2

__device__ __forceinline__ void atomAddF(float* p, float v) {
    unsafeAtomicAdd(p, v);   // HW global_atomic_add_f32
}

// ---- degree + histogram ----------------------------------------------------
__global__ void k_deg_init(float* __restrict__ deg, int* __restrict__ cnt, int n) {
    int i = blockIdx.x * 256 + threadIdx.x;
    if (i < n) { deg[i] = 1.0f; cnt[i] = 0; }   // self-loop weight, zero hist
}

__global__ void k_deg_hist(const int* __restrict__ ei, const float* __restrict__ w,
                           float* __restrict__ deg, int* __restrict__ cnt, int E) {
    int e = blockIdx.x * 256 + threadIdx.x;
    if (e < E) {
        int d = ei[E + e];
        atomAddF(&deg[d], w[e]);
        atomicAdd(&cnt[d], 1);
    }
}

__global__ void k_dinv(float* __restrict__ deg, int n) {
    int i = blockIdx.x * 256 + threadIdx.x;
    if (i < n) { float d = deg[i]; deg[i] = d > 0.f ? rsqrtf(d) : 0.f; }
}

// ---- exclusive scan of cnt -> rowptr (1024 elems / block) ------------------
__global__ __launch_bounds__(256) void k_scanA(const int* __restrict__ cnt,
                                               int* __restrict__ excl,
                                               int* __restrict__ bsum, int n) {
    __shared__ int ss[256];
    int t = threadIdx.x;
    int base = blockIdx.x * 1024 + t * 4;
    int v0 = 0, v1 = 0, v2 = 0, v3 = 0;
    if (base + 0 < n) v0 = cnt[base + 0];
    if (base + 1 < n) v1 = cnt[base + 1];
    if (base + 2 < n) v2 = cnt[base + 2];
    if (base + 3 < n) v3 = cnt[base + 3];
    ss[t] = v0 + v1 + v2 + v3;
    __syncthreads();
    for (int d = 1; d < 256; d <<= 1) {
        int x = (t >= d) ? ss[t - d] : 0;
        __syncthreads();
        ss[t] += x;
        __syncthreads();
    }
    int pre = (t == 0) ? 0 : ss[t - 1];
    if (t == 255) bsum[blockIdx.x] = ss[255];
    if (base + 0 < n) excl[base + 0] = pre;
    if (base + 1 < n) excl[base + 1] = pre + v0;
    if (base + 2 < n) excl[base + 2] = pre + v0 + v1;
    if (base + 3 < n) excl[base + 3] = pre + v0 + v1 + v2;
}

__global__ __launch_bounds__(256) void k_scanB(int* __restrict__ bsum, int nb) {
    __shared__ int ss[256];
    int t = threadIdx.x;
    int v = (t < nb) ? bsum[t] : 0;
    ss[t] = v;
    __syncthreads();
    for (int d = 1; d < 256; d <<= 1) {
        int x = (t >= d) ? ss[t - d] : 0;
        __syncthreads();
        ss[t] += x;
        __syncthreads();
    }
    if (t < nb) bsum[t] = ss[t] - v;   // exclusive
}

__global__ void k_scanC(int* __restrict__ rowptr, int* __restrict__ cursor,
                        const int* __restrict__ bsum, int n, int E) {
    int i = blockIdx.x * 256 + threadIdx.x;
    if (i < n) {
        int v = rowptr[i] + bsum[i >> 10];
        rowptr[i] = v;
        cursor[i] = v;
    }
    if (i == 0) rowptr[n] = E;
}

// ---- bucket scatter: edata[pos] = {src, norm} sorted by dst ---------------
__global__ void k_build(const int* __restrict__ ei, const float* __restrict__ w,
                        const float* __restrict__ dinv, int* __restrict__ cursor,
                        int2* __restrict__ edata, int E) {
    int e = blockIdx.x * 256 + threadIdx.x;
    if (e >= E) return;
    int s = ei[e], d = ei[E + e];
    float nm = dinv[s] * w[e] * dinv[d];
    int pos = atomicAdd(&cursor[d], 1);
    edata[pos] = make_int2(s, __float_as_int(nm));
}

// ---- GEMM1: h1[N,128] = x[N,256] @ W1[256,128] -----------------------------
// Register-blocked: 64x128 tile/block, K chunked by 32, 4x8 micro-tile/thread.
#define XS_LD 36    // 64 x 36 floats, 16B-aligned rows, bank-offset 4
#define WS_LD 132   // 32 x 132 floats, 16B-aligned rows (528 B)
__global__ __launch_bounds__(256) void k_gemm1(const float* __restrict__ x,
                                               const float* __restrict__ W1,
                                               float* __restrict__ h1, int n) {
    __shared__ float xs[64 * XS_LD];
    __shared__ float ws[32 * WS_LD];
    int tid  = threadIdx.x;
    int row0 = blockIdx.x * 64;
    int tr   = tid >> 4;          // 0..15 -> rows tr*4 .. tr*4+3
    int tc   = tid & 15;          // 0..15 -> cols tc*8 .. tc*8+7

    float acc[4][8];
#pragma unroll
    for (int j = 0; j < 4; j++)
#pragma unroll
        for (int c = 0; c < 8; c++) acc[j][c] = 0.f;

    for (int k0 = 0; k0 < IN_C; k0 += 32) {
        // stage x[row0..row0+63][k0..k0+31] -> xs
        {
            int r  = tid >> 3;           // 0..31
            int c4 = tid & 7;            // 0..7 -> 4 floats
#pragma unroll
            for (int p = 0; p < 2; p++) {
                int rr = r + p * 32;
                if (row0 + rr < n) {
                    float4 v = *((const float4*)(x + (size_t)(row0 + rr) * IN_C + k0 + c4 * 4));
                    *((float4*)&xs[rr * XS_LD + c4 * 4]) = v;
                }
            }
        }
        // stage W1[k0..k0+31][0..127] -> ws
        {
#pragma unroll
            for (int p = 0; p < 4; p++) {
                int idx = p * 256 + tid;
                int k = idx >> 5, c = idx & 31;
                float4 v = *((const float4*)(W1 + (size_t)(k0 + k) * HID_C + c * 4));
                *((float4*)&ws[k * WS_LD + c * 4]) = v;
            }
        }
        __syncthreads();
#pragma unroll 8
        for (int k = 0; k < 32; k++) {
            float x0 = xs[(tr * 4 + 0) * XS_LD + k];
            float x1 = xs[(tr * 4 + 1) * XS_LD + k];
            float x2 = xs[(tr * 4 + 2) * XS_LD + k];
            float x3 = xs[(tr * 4 + 3) * XS_LD + k];
            float4 wa = *((const float4*)&ws[k * WS_LD + tc * 8]);
            float4 wb = *((const float4*)&ws[k * WS_LD + tc * 8 + 4]);
            acc[0][0] = fmaf(x0, wa.x, acc[0][0]); acc[0][1] = fmaf(x0, wa.y, acc[0][1]);
            acc[0][2] = fmaf(x0, wa.z, acc[0][2]); acc[0][3] = fmaf(x0, wa.w, acc[0][3]);
            acc[0][4] = fmaf(x0, wb.x, acc[0][4]); acc[0][5] = fmaf(x0, wb.y, acc[0][5]);
            acc[0][6] = fmaf(x0, wb.z, acc[0][6]); acc[0][7] = fmaf(x0, wb.w, acc[0][7]);
            acc[1][0] = fmaf(x1, wa.x, acc[1][0]); acc[1][1] = fmaf(x1, wa.y, acc[1][1]);
            acc[1][2] = fmaf(x1, wa.z, acc[1][2]); acc[1][3] = fmaf(x1, wa.w, acc[1][3]);
            acc[1][4] = fmaf(x1, wb.x, acc[1][4]); acc[1][5] = fmaf(x1, wb.y, acc[1][5]);
            acc[1][6] = fmaf(x1, wb.z, acc[1][6]); acc[1][7] = fmaf(x1, wb.w, acc[1][7]);
            acc[2][0] = fmaf(x2, wa.x, acc[2][0]); acc[2][1] = fmaf(x2, wa.y, acc[2][1]);
            acc[2][2] = fmaf(x2, wa.z, acc[2][2]); acc[2][3] = fmaf(x2, wa.w, acc[2][3]);
            acc[2][4] = fmaf(x2, wb.x, acc[2][4]); acc[2][5] = fmaf(x2, wb.y, acc[2][5]);
            acc[2][6] = fmaf(x2, wb.z, acc[2][6]); acc[2][7] = fmaf(x2, wb.w, acc[2][7]);
            acc[3][0] = fmaf(x3, wa.x, acc[3][0]); acc[3][1] = fmaf(x3, wa.y, acc[3][1]);
            acc[3][2] = fmaf(x3, wa.z, acc[3][2]); acc[3][3] = fmaf(x3, wa.w, acc[3][3]);
            acc[3][4] = fmaf(x3, wb.x, acc[3][4]); acc[3][5] = fmaf(x3, wb.y, acc[3][5]);
            acc[3][6] = fmaf(x3, wb.z, acc[3][6]); acc[3][7] = fmaf(x3, wb.w, acc[3][7]);
        }
        __syncthreads();
    }
#pragma unroll
    for (int j = 0; j < 4; j++) {
        int row = row0 + tr * 4 + j;
        if (row < n) {
            float4* o = (float4*)(h1 + (size_t)row * HID_C + tc * 8);
            o[0] = make_float4(acc[j][0], acc[j][1], acc[j][2], acc[j][3]);
            o[1] = make_float4(acc[j][4], acc[j][5], acc[j][6], acc[j][7]);
        }
    }
}

// ---- layer-1 aggregation: one wave per dst node, no atomics ---------------
__global__ __launch_bounds__(256) void k_agg1(const int* __restrict__ rowptr,
                                              const int2* __restrict__ edata,
                                              const float* __restrict__ h1,
                                              const float* __restrict__ dinv,
                                              const float* __restrict__ b1,
                                              float* __restrict__ agg1, int n) {
    int wid  = (blockIdx.x * 256 + threadIdx.x) >> 6;   // node id
    int lane = threadIdx.x & 63;                        // owns cols 2*lane, 2*lane+1
    if (wid >= n) return;
    int beg = rowptr[wid], end = rowptr[wid + 1];
    float2 acc = make_float2(0.f, 0.f);
    int j = beg;
    for (; j + 8 <= end; j += 8) {            // 8-deep ILP on the gather
        int2 e[8];
        float2 v[8];
#pragma unroll
        for (int q = 0; q < 8; q++) e[q] = edata[j + q];
#pragma unroll
        for (int q = 0; q < 8; q++)
            v[q] = ((const float2*)(h1 + (size_t)e[q].x * HID_C))[lane];
#pragma unroll
        for (int q = 0; q < 8; q++) {
            float nm = __int_as_float(e[q].y);
            acc.x = fmaf(nm, v[q].x, acc.x);
            acc.y = fmaf(nm, v[q].y, acc.y);
        }
    }
    for (; j < end; j++) {
        int2 e0 = edata[j];
        float2 v0 = ((const float2*)(h1 + (size_t)e0.x * HID_C))[lane];
        float n0 = __int_as_float(e0.y);
        acc.x = fmaf(n0, v0.x, acc.x); acc.y = fmaf(n0, v0.y, acc.y);
    }
    float di = dinv[wid]; float sc = di * di;           // self-loop norm
    float2 hv = ((const float2*)(h1 + (size_t)wid * HID_C))[lane];
    float2 bv = ((const float2*)b1)[lane];
    acc.x += bv.x + sc * hv.x;
    acc.y += bv.y + sc * hv.y;
    ((float2*)(agg1 + (size_t)wid * HID_C))[lane] = acc;
}

// ---- GEMM2: h2[N,2] = relu(agg1) @ W2[128,2] -------------------------------
__global__ __launch_bounds__(256) void k_gemm2(const float* __restrict__ agg1,
                                               const float* __restrict__ W2,
                                               float* __restrict__ h2, int n) {
    int lane = threadIdx.x & 63;
    int wave = threadIdx.x >> 6;
    int node = blockIdx.x * 8 + wave * 2 + (lane >> 5);
    int l = lane & 31;
    float s0 = 0.f, s1 = 0.f;
    if (node < n) {
        float4 v = ((const float4*)(agg1 + (size_t)node * HID_C))[l];
        v.x = fmaxf(v.x, 0.f); v.y = fmaxf(v.y, 0.f);
        v.z = fmaxf(v.z, 0.f); v.w = fmaxf(v.w, 0.f);
        const float2* w2 = (const float2*)W2;
        float2 w0 = w2[l * 4 + 0], w1 = w2[l * 4 + 1];
        float2 wq = w2[l * 4 + 2], w3 = w2[l * 4 + 3];
        s0 = v.x * w0.x + v.y * w1.x + v.z * wq.x + v.w * w3.x;
        s1 = v.x * w0.y + v.y * w1.y + v.z * wq.y + v.w * w3.y;
    }
#pragma unroll
    for (int d = 16; d > 0; d >>= 1) {
        s0 += __shfl_down(s0, d, 32);
        s1 += __shfl_down(s1, d, 32);
    }
    if (node < n && l == 0)
        ((float2*)h2)[node] = make_float2(s0, s1);
}

// ---- layer-2 aggregation: wave per node, lanes over edges ------------------
__global__ __launch_bounds__(256) void k_agg2(const int* __restrict__ rowptr,
                                              const int2* __restrict__ edata,
                                              const float* __restrict__ h2,
                                              const float* __restrict__ dinv,
                                              const float* __restrict__ b2,
                                              float* __restrict__ out, int n) {
    int wid  = (blockIdx.x * 256 + threadIdx.x) >> 6;
    int lane = threadIdx.x & 63;
    if (wid >= n) return;
    int beg = rowptr[wid], end = rowptr[wid + 1];
    float sx = 0.f, sy = 0.f;
    for (int j = beg + lane; j < end; j += 64) {
        int2 ed = edata[j];
        float nm = __int_as_float(ed.y);
        float2 v = ((const float2*)h2)[ed.x];
        sx = fmaf(nm, v.x, sx);
        sy = fmaf(nm, v.y, sy);
    }
#pragma unroll
    for (int d = 32; d > 0; d >>= 1) {
        sx += __shfl_xor(sx, d);
        sy += __shfl_xor(sy, d);
    }
    if (lane == 0) {
        float di = dinv[wid]; float sc = di * di;
        float2 hv = ((const float2*)h2)[wid];
        ((float2*)out)[wid] = make_float2(b2[0] + sc * hv.x + sx,
                                          b2[1] + sc * hv.y + sy);
    }
}

extern "C" void kernel_launch(void* const* d_in, const int* in_sizes, int n_in,
                              void* d_out, int out_size, void* d_ws, size_t ws_size,
                              hipStream_t stream) {
    const float* x  = (const float*)d_in[0];
    const int*   ei = (const int*)d_in[1];   // [2,E] int32: src = ei[0:E], dst = ei[E:2E]
    const float* ew = (const float*)d_in[2];
    const float* W1 = (const float*)d_in[3];
    const float* b1 = (const float*)d_in[4];
    const float* W2 = (const float*)d_in[5];
    const float* b2 = (const float*)d_in[6];
    float* out = (float*)d_out;

    int N = in_sizes[0] / IN_C;
    int E = in_sizes[2];

    char* ws = (char*)d_ws;
    float* dinv   = (float*)ws; ws += (size_t)N * 4;
    int*   cnt    = (int*)ws;   ws += (size_t)N * 4;
    int*   rowptr = (int*)ws;   ws += (size_t)(N + 1) * 4 + 4;   // keep 8B align
    int*   cursor = (int*)ws;   ws += (size_t)N * 4;
    int*   bsum   = (int*)ws;   ws += 1024;
    int2*  edata  = (int2*)ws;  ws += (size_t)E * 8;
    float* h1     = (float*)ws; ws += (size_t)N * HID_C * 4;
    float* agg1   = (float*)ws; ws += (size_t)N * HID_C * 4;
    float* h2     = (float*)ws; ws += (size_t)N * OUT_C * 4;

    int nb_n = (N + 255) / 256;
    int nb_e = (E + 255) / 256;
    int nb_s = (N + 1023) / 1024;            // scan blocks (<= 256 supported)
    int nb_w = (N * 64 + 255) / 256;         // wave-per-node grids

    k_deg_init<<<nb_n, 256, 0, stream>>>(dinv, cnt, N);
    k_deg_hist<<<nb_e, 256, 0, stream>>>(ei, ew, dinv, cnt, E);
    k_dinv    <<<nb_n, 256, 0, stream>>>(dinv, N);
    k_scanA   <<<nb_s, 256, 0, stream>>>(cnt, rowptr, bsum, N);
    k_scanB   <<<1,    256, 0, stream>>>(bsum, nb_s);
    k_scanC   <<<nb_n, 256, 0, stream>>>(rowptr, cursor, bsum, N, E);
    k_build   <<<nb_e, 256, 0, stream>>>(ei, ew, dinv, cursor, edata, E);
    k_gemm1   <<<(N + 63) / 64, 256, 0, stream>>>(x, W1, h1, N);
    k_agg1    <<<nb_w, 256, 0, stream>>>(rowptr, edata, h1, dinv, b1, agg1, N);
    k_gemm2   <<<(N + 7) / 8, 256, 0, stream>>>(agg1, W2, h2, N);
    k_agg2    <<<nb_w, 256, 0, stream>>>(rowptr, edata, h2, dinv, b2, out, N);
}

// Round 4
// 962.850 us; speedup vs baseline: 6.5456x; 1.0172x over previous
//
#include <hip/hip_runtime.h>

#define IN_C  256
#define HID_C 128
#define OUT_C 2

// ---- histogram (int only; float deg now computed by CSR row-sum) -----------
__global__ void k_zero(int* __restrict__ cnt, int n) {
    int i = blockIdx.x * 256 + threadIdx.x;
    if (i < n) cnt[i] = 0;
}

__global__ void k_hist(const int* __restrict__ ei, int* __restrict__ cnt, int E) {
    int e = blockIdx.x * 256 + threadIdx.x;
    if (e < E) atomicAdd(&cnt[ei[E + e]], 1);
}

// ---- exclusive scan of cnt -> rowptr (1024 elems / block) ------------------
__global__ __launch_bounds__(256) void k_scanA(const int* __restrict__ cnt,
                                               int* __restrict__ excl,
                                               int* __restrict__ bsum, int n) {
    __shared__ int ss[256];
    int t = threadIdx.x;
    int base = blockIdx.x * 1024 + t * 4;
    int v0 = 0, v1 = 0, v2 = 0, v3 = 0;
    if (base + 0 < n) v0 = cnt[base + 0];
    if (base + 1 < n) v1 = cnt[base + 1];
    if (base + 2 < n) v2 = cnt[base + 2];
    if (base + 3 < n) v3 = cnt[base + 3];
    ss[t] = v0 + v1 + v2 + v3;
    __syncthreads();
    for (int d = 1; d < 256; d <<= 1) {
        int x = (t >= d) ? ss[t - d] : 0;
        __syncthreads();
        ss[t] += x;
        __syncthreads();
    }
    int pre = (t == 0) ? 0 : ss[t - 1];
    if (t == 255) bsum[blockIdx.x] = ss[255];
    if (base + 0 < n) excl[base + 0] = pre;
    if (base + 1 < n) excl[base + 1] = pre + v0;
    if (base + 2 < n) excl[base + 2] = pre + v0 + v1;
    if (base + 3 < n) excl[base + 3] = pre + v0 + v1 + v2;
}

__global__ __launch_bounds__(256) void k_scanB(int* __restrict__ bsum, int nb) {
    __shared__ int ss[256];
    int t = threadIdx.x;
    int v = (t < nb) ? bsum[t] : 0;
    ss[t] = v;
    __syncthreads();
    for (int d = 1; d < 256; d <<= 1) {
        int x = (t >= d) ? ss[t - d] : 0;
        __syncthreads();
        ss[t] += x;
        __syncthreads();
    }
    if (t < nb) bsum[t] = ss[t] - v;   // exclusive
}

__global__ void k_scanC(int* __restrict__ rowptr, int* __restrict__ cursor,
                        const int* __restrict__ bsum, int n, int E) {
    int i = blockIdx.x * 256 + threadIdx.x;
    if (i < n) {
        int v = rowptr[i] + bsum[i >> 10];
        rowptr[i] = v;
        cursor[i] = v;
    }
    if (i == 0) rowptr[n] = E;
}

// ---- bucket scatter: edata[pos] = {src, w} sorted by dst (pre-dinv) -------
__global__ void k_build(const int* __restrict__ ei, const float* __restrict__ w,
                        int* __restrict__ cursor, int2* __restrict__ edata, int E) {
    int e = blockIdx.x * 256 + threadIdx.x;
    if (e >= E) return;
    int s = ei[e], d = ei[E + e];
    int pos = atomicAdd(&cursor[d], 1);
    edata[pos] = make_int2(s, __float_as_int(w[e]));
}

// ---- deg by CSR row-sum (no atomics), fused rsqrt -------------------------
__global__ void k_degrow(const int* __restrict__ rowptr, const int2* __restrict__ edata,
                         float* __restrict__ dinv, int n) {
    int i = blockIdx.x * 256 + threadIdx.x;
    if (i >= n) return;
    int beg = rowptr[i], end = rowptr[i + 1];
    float s = 1.0f;                               // self-loop weight
    for (int j = beg; j < end; j++) s += __int_as_float(edata[j].y);
    dinv[i] = s > 0.f ? rsqrtf(s) : 0.f;
}

// ---- scale edge weights by dinv[src] (dinv[dst] applied in agg epilogue) --
__global__ void k_scale(int2* __restrict__ edata, const float* __restrict__ dinv, int E) {
    int i = blockIdx.x * 256 + threadIdx.x;
    if (i >= E) return;
    int2 e = edata[i];
    e.y = __float_as_int(__int_as_float(e.y) * dinv[e.x]);
    edata[i] = e;
}

// ---- GEMM1: h1[N,128] = x[N,256] @ W1[256,128] -----------------------------
// Register-blocked: 64x128 tile/block, K chunked by 32, 4x8 micro-tile/thread.
#define XS_LD 36
#define WS_LD 132
__global__ __launch_bounds__(256) void k_gemm1(const float* __restrict__ x,
                                               const float* __restrict__ W1,
                                               float* __restrict__ h1, int n) {
    __shared__ float xs[64 * XS_LD];
    __shared__ float ws[32 * WS_LD];
    int tid  = threadIdx.x;
    int row0 = blockIdx.x * 64;
    int tr   = tid >> 4;
    int tc   = tid & 15;

    float acc[4][8];
#pragma unroll
    for (int j = 0; j < 4; j++)
#pragma unroll
        for (int c = 0; c < 8; c++) acc[j][c] = 0.f;

    for (int k0 = 0; k0 < IN_C; k0 += 32) {
        {
            int r  = tid >> 3;
            int c4 = tid & 7;
#pragma unroll
            for (int p = 0; p < 2; p++) {
                int rr = r + p * 32;
                if (row0 + rr < n) {
                    float4 v = *((const float4*)(x + (size_t)(row0 + rr) * IN_C + k0 + c4 * 4));
                    *((float4*)&xs[rr * XS_LD + c4 * 4]) = v;
                }
            }
        }
        {
#pragma unroll
            for (int p = 0; p < 4; p++) {
                int idx = p * 256 + tid;
                int k = idx >> 5, c = idx & 31;
                float4 v = *((const float4*)(W1 + (size_t)(k0 + k) * HID_C + c * 4));
                *((float4*)&ws[k * WS_LD + c * 4]) = v;
            }
        }
        __syncthreads();
#pragma unroll 8
        for (int k = 0; k < 32; k++) {
            float x0 = xs[(tr * 4 + 0) * XS_LD + k];
            float x1 = xs[(tr * 4 + 1) * XS_LD + k];
            float x2 = xs[(tr * 4 + 2) * XS_LD + k];
            float x3 = xs[(tr * 4 + 3) * XS_LD + k];
            float4 wa = *((const float4*)&ws[k * WS_LD + tc * 8]);
            float4 wb = *((const float4*)&ws[k * WS_LD + tc * 8 + 4]);
            acc[0][0] = fmaf(x0, wa.x, acc[0][0]); acc[0][1] = fmaf(x0, wa.y, acc[0][1]);
            acc[0][2] = fmaf(x0, wa.z, acc[0][2]); acc[0][3] = fmaf(x0, wa.w, acc[0][3]);
            acc[0][4] = fmaf(x0, wb.x, acc[0][4]); acc[0][5] = fmaf(x0, wb.y, acc[0][5]);
            acc[0][6] = fmaf(x0, wb.z, acc[0][6]); acc[0][7] = fmaf(x0, wb.w, acc[0][7]);
            acc[1][0] = fmaf(x1, wa.x, acc[1][0]); acc[1][1] = fmaf(x1, wa.y, acc[1][1]);
            acc[1][2] = fmaf(x1, wa.z, acc[1][2]); acc[1][3] = fmaf(x1, wa.w, acc[1][3]);
            acc[1][4] = fmaf(x1, wb.x, acc[1][4]); acc[1][5] = fmaf(x1, wb.y, acc[1][5]);
            acc[1][6] = fmaf(x1, wb.z, acc[1][6]); acc[1][7] = fmaf(x1, wb.w, acc[1][7]);
            acc[2][0] = fmaf(x2, wa.x, acc[2][0]); acc[2][1] = fmaf(x2, wa.y, acc[2][1]);
            acc[2][2] = fmaf(x2, wa.z, acc[2][2]); acc[2][3] = fmaf(x2, wa.w, acc[2][3]);
            acc[2][4] = fmaf(x2, wb.x, acc[2][4]); acc[2][5] = fmaf(x2, wb.y, acc[2][5]);
            acc[2][6] = fmaf(x2, wb.z, acc[2][6]); acc[2][7] = fmaf(x2, wb.w, acc[2][7]);
            acc[3][0] = fmaf(x3, wa.x, acc[3][0]); acc[3][1] = fmaf(x3, wa.y, acc[3][1]);
            acc[3][2] = fmaf(x3, wa.z, acc[3][2]); acc[3][3] = fmaf(x3, wa.w, acc[3][3]);
            acc[3][4] = fmaf(x3, wb.x, acc[3][4]); acc[3][5] = fmaf(x3, wb.y, acc[3][5]);
            acc[3][6] = fmaf(x3, wb.z, acc[3][6]); acc[3][7] = fmaf(x3, wb.w, acc[3][7]);
        }
        __syncthreads();
    }
#pragma unroll
    for (int j = 0; j < 4; j++) {
        int row = row0 + tr * 4 + j;
        if (row < n) {
            float4* o = (float4*)(h1 + (size_t)row * HID_C + tc * 8);
            o[0] = make_float4(acc[j][0], acc[j][1], acc[j][2], acc[j][3]);
            o[1] = make_float4(acc[j][4], acc[j][5], acc[j][6], acc[j][7]);
        }
    }
}

// ---- layer-1 aggregation: one wave per dst node, no atomics ---------------
// edata.y already holds dinv[src]*w; dinv[dst] applied in epilogue.
__global__ __launch_bounds__(256) void k_agg1(const int* __restrict__ rowptr,
                                              const int2* __restrict__ edata,
                                              const float* __restrict__ h1,
                                              const float* __restrict__ dinv,
                                              const float* __restrict__ b1,
                                              float* __restrict__ agg1, int n) {
    int wid  = (blockIdx.x * 256 + threadIdx.x) >> 6;   // node id
    int lane = threadIdx.x & 63;                        // owns cols 2*lane, 2*lane+1
    if (wid >= n) return;
    int beg = rowptr[wid], end = rowptr[wid + 1];
    float2 acc = make_float2(0.f, 0.f);
    int j = beg;
    for (; j + 8 <= end; j += 8) {
        int2 e[8];
        float2 v[8];
#pragma unroll
        for (int q = 0; q < 8; q++) e[q] = edata[j + q];
#pragma unroll
        for (int q = 0; q < 8; q++)
            v[q] = ((const float2*)(h1 + (size_t)e[q].x * HID_C))[lane];
#pragma unroll
        for (int q = 0; q < 8; q++) {
            float nm = __int_as_float(e[q].y);
            acc.x = fmaf(nm, v[q].x, acc.x);
            acc.y = fmaf(nm, v[q].y, acc.y);
        }
    }
    for (; j < end; j++) {
        int2 e0 = edata[j];
        float2 v0 = ((const float2*)(h1 + (size_t)e0.x * HID_C))[lane];
        float n0 = __int_as_float(e0.y);
        acc.x = fmaf(n0, v0.x, acc.x); acc.y = fmaf(n0, v0.y, acc.y);
    }
    float di = dinv[wid]; float sc = di * di;
    float2 hv = ((const float2*)(h1 + (size_t)wid * HID_C))[lane];
    float2 bv = ((const float2*)b1)[lane];
    acc.x = bv.x + sc * hv.x + di * acc.x;
    acc.y = bv.y + sc * hv.y + di * acc.y;
    ((float2*)(agg1 + (size_t)wid * HID_C))[lane] = acc;
}

// ---- GEMM2: h2[N,2] = relu(agg1) @ W2[128,2] -------------------------------
__global__ __launch_bounds__(256) void k_gemm2(const float* __restrict__ agg1,
                                               const float* __restrict__ W2,
                                               float* __restrict__ h2, int n) {
    int lane = threadIdx.x & 63;
    int wave = threadIdx.x >> 6;
    int node = blockIdx.x * 8 + wave * 2 + (lane >> 5);
    int l = lane & 31;
    float s0 = 0.f, s1 = 0.f;
    if (node < n) {
        float4 v = ((const float4*)(agg1 + (size_t)node * HID_C))[l];
        v.x = fmaxf(v.x, 0.f); v.y = fmaxf(v.y, 0.f);
        v.z = fmaxf(v.z, 0.f); v.w = fmaxf(v.w, 0.f);
        const float2* w2 = (const float2*)W2;
        float2 w0 = w2[l * 4 + 0], w1 = w2[l * 4 + 1];
        float2 wq = w2[l * 4 + 2], w3 = w2[l * 4 + 3];
        s0 = v.x * w0.x + v.y * w1.x + v.z * wq.x + v.w * w3.x;
        s1 = v.x * w0.y + v.y * w1.y + v.z * wq.y + v.w * w3.y;
    }
#pragma unroll
    for (int d = 16; d > 0; d >>= 1) {
        s0 += __shfl_down(s0, d, 32);
        s1 += __shfl_down(s1, d, 32);
    }
    if (node < n && l == 0)
        ((float2*)h2)[node] = make_float2(s0, s1);
}

// ---- layer-2 aggregation: wave per node, lanes over edges ------------------
__global__ __launch_bounds__(256) void k_agg2(const int* __restrict__ rowptr,
                                              const int2* __restrict__ edata,
                                              const float* __restrict__ h2,
                                              const float* __restrict__ dinv,
                                              const float* __restrict__ b2,
                                              float* __restrict__ out, int n) {
    int wid  = (blockIdx.x * 256 + threadIdx.x) >> 6;
    int lane = threadIdx.x & 63;
    if (wid >= n) return;
    int beg = rowptr[wid], end = rowptr[wid + 1];
    float sx = 0.f, sy = 0.f;
    for (int j = beg + lane; j < end; j += 64) {
        int2 ed = edata[j];
        float nm = __int_as_float(ed.y);
        float2 v = ((const float2*)h2)[ed.x];
        sx = fmaf(nm, v.x, sx);
        sy = fmaf(nm, v.y, sy);
    }
#pragma unroll
    for (int d = 32; d > 0; d >>= 1) {
        sx += __shfl_xor(sx, d);
        sy += __shfl_xor(sy, d);
    }
    if (lane == 0) {
        float di = dinv[wid]; float sc = di * di;
        float2 hv = ((const float2*)h2)[wid];
        ((float2*)out)[wid] = make_float2(b2[0] + sc * hv.x + di * sx,
                                          b2[1] + sc * hv.y + di * sy);
    }
}

extern "C" void kernel_launch(void* const* d_in, const int* in_sizes, int n_in,
                              void* d_out, int out_size, void* d_ws, size_t ws_size,
                              hipStream_t stream) {
    const float* x  = (const float*)d_in[0];
    const int*   ei = (const int*)d_in[1];   // [2,E] int32: src = ei[0:E], dst = ei[E:2E]
    const float* ew = (const float*)d_in[2];
    const float* W1 = (const float*)d_in[3];
    const float* b1 = (const float*)d_in[4];
    const float* W2 = (const float*)d_in[5];
    const float* b2 = (const float*)d_in[6];
    float* out = (float*)d_out;

    int N = in_sizes[0] / IN_C;
    int E = in_sizes[2];

    char* ws = (char*)d_ws;
    float* dinv   = (float*)ws; ws += (size_t)N * 4;
    int*   cnt    = (int*)ws;   ws += (size_t)N * 4;
    int*   rowptr = (int*)ws;   ws += (size_t)(N + 1) * 4 + 4;   // keep 8B align
    int*   cursor = (int*)ws;   ws += (size_t)N * 4;
    int*   bsum   = (int*)ws;   ws += 1024;
    int2*  edata  = (int2*)ws;  ws += (size_t)E * 8;
    float* h1     = (float*)ws; ws += (size_t)N * HID_C * 4;
    float* agg1   = (float*)ws; ws += (size_t)N * HID_C * 4;
    float* h2     = (float*)ws; ws += (size_t)N * OUT_C * 4;

    int nb_n = (N + 255) / 256;
    int nb_e = (E + 255) / 256;
    int nb_s = (N + 1023) / 1024;
    int nb_w = (N * 64 + 255) / 256;

    k_zero  <<<nb_n, 256, 0, stream>>>(cnt, N);
    k_hist  <<<nb_e, 256, 0, stream>>>(ei, cnt, E);
    k_scanA <<<nb_s, 256, 0, stream>>>(cnt, rowptr, bsum, N);
    k_scanB <<<1,    256, 0, stream>>>(bsum, nb_s);
    k_scanC <<<nb_n, 256, 0, stream>>>(rowptr, cursor, bsum, N, E);
    k_build <<<nb_e, 256, 0, stream>>>(ei, ew, cursor, edata, E);
    k_degrow<<<nb_n, 256, 0, stream>>>(rowptr, edata, dinv, N);
    k_scale <<<nb_e, 256, 0, stream>>>(edata, dinv, E);
    k_gemm1 <<<(N + 63) / 64, 256, 0, stream>>>(x, W1, h1, N);
    k_agg1  <<<nb_w, 256, 0, stream>>>(rowptr, edata, h1, dinv, b1, agg1, N);
    k_gemm2 <<<(N + 7) / 8, 256, 0, stream>>>(agg1, W2, h2, N);
    k_agg2  <<<nb_w, 256, 0, stream>>>(rowptr, edata, h2, dinv, b2, out, N);
}

// Round 5
// 857.634 us; speedup vs baseline: 7.3486x; 1.1227x over previous
//
#include <hip/hip_runtime.h>

#define IN_C  256
#define HID_C 128
#define OUT_C 2

__device__ __forceinline__ unsigned short f2bf(float f) {   // RNE float->bf16
    unsigned u = __float_as_uint(f);
    unsigned r = 0x7fffu + ((u >> 16) & 1u);
    return (unsigned short)((u + r) >> 16);
}

// ---- histogram -------------------------------------------------------------
__global__ void k_zero(int* __restrict__ cnt, int n) {
    int i = blockIdx.x * 256 + threadIdx.x;
    if (i < n) cnt[i] = 0;
}

__global__ void k_hist(const int* __restrict__ ei, int* __restrict__ cnt, int E) {
    int e = blockIdx.x * 256 + threadIdx.x;
    if (e < E) atomicAdd(&cnt[ei[E + e]], 1);
}

// ---- exclusive scan of cnt -> rowptr (1024 elems / block) ------------------
__global__ __launch_bounds__(256) void k_scanA(const int* __restrict__ cnt,
                                               int* __restrict__ excl,
                                               int* __restrict__ bsum, int n) {
    __shared__ int ss[256];
    int t = threadIdx.x;
    int base = blockIdx.x * 1024 + t * 4;
    int v0 = 0, v1 = 0, v2 = 0, v3 = 0;
    if (base + 0 < n) v0 = cnt[base + 0];
    if (base + 1 < n) v1 = cnt[base + 1];
    if (base + 2 < n) v2 = cnt[base + 2];
    if (base + 3 < n) v3 = cnt[base + 3];
    ss[t] = v0 + v1 + v2 + v3;
    __syncthreads();
    for (int d = 1; d < 256; d <<= 1) {
        int x = (t >= d) ? ss[t - d] : 0;
        __syncthreads();
        ss[t] += x;
        __syncthreads();
    }
    int pre = (t == 0) ? 0 : ss[t - 1];
    if (t == 255) bsum[blockIdx.x] = ss[255];
    if (base + 0 < n) excl[base + 0] = pre;
    if (base + 1 < n) excl[base + 1] = pre + v0;
    if (base + 2 < n) excl[base + 2] = pre + v0 + v1;
    if (base + 3 < n) excl[base + 3] = pre + v0 + v1 + v2;
}

__global__ __launch_bounds__(256) void k_scanB(int* __restrict__ bsum, int nb) {
    __shared__ int ss[256];
    int t = threadIdx.x;
    int v = (t < nb) ? bsum[t] : 0;
    ss[t] = v;
    __syncthreads();
    for (int d = 1; d < 256; d <<= 1) {
        int x = (t >= d) ? ss[t - d] : 0;
        __syncthreads();
        ss[t] += x;
        __syncthreads();
    }
    if (t < nb) bsum[t] = ss[t] - v;   // exclusive
}

__global__ void k_scanC(int* __restrict__ rowptr, int* __restrict__ cursor,
                        const int* __restrict__ bsum, int n, int E) {
    int i = blockIdx.x * 256 + threadIdx.x;
    if (i < n) {
        int v = rowptr[i] + bsum[i >> 10];
        rowptr[i] = v;
        cursor[i] = v;
    }
    if (i == 0) rowptr[n] = E;
}

// ---- bucket scatter: edata[pos] = {src, w} sorted by dst (pre-dinv) -------
__global__ void k_build(const int* __restrict__ ei, const float* __restrict__ w,
                        int* __restrict__ cursor, int2* __restrict__ edata, int E) {
    int e = blockIdx.x * 256 + threadIdx.x;
    if (e >= E) return;
    int s = ei[e], d = ei[E + e];
    int pos = atomicAdd(&cursor[d], 1);
    edata[pos] = make_int2(s, __float_as_int(w[e]));
}

// ---- deg by CSR row-sum (no atomics), fused rsqrt -------------------------
__global__ void k_degrow(const int* __restrict__ rowptr, const int2* __restrict__ edata,
                         float* __restrict__ dinv, int n) {
    int i = blockIdx.x * 256 + threadIdx.x;
    if (i >= n) return;
    int beg = rowptr[i], end = rowptr[i + 1];
    float s = 1.0f;                               // self-loop weight
    for (int j = beg; j < end; j++) s += __int_as_float(edata[j].y);
    dinv[i] = s > 0.f ? rsqrtf(s) : 0.f;
}

// ---- scale edge weights by dinv[src] --------------------------------------
__global__ void k_scale(int2* __restrict__ edata, const float* __restrict__ dinv, int E) {
    int i = blockIdx.x * 256 + threadIdx.x;
    if (i >= E) return;
    int2 e = edata[i];
    e.y = __float_as_int(__int_as_float(e.y) * dinv[e.x]);
    edata[i] = e;
}

// ---- GEMM1: h1b[N,128] (bf16) = x[N,256] @ W1[256,128] ---------------------
#define XS_LD 36
#define WS_LD 132
__global__ __launch_bounds__(256) void k_gemm1(const float* __restrict__ x,
                                               const float* __restrict__ W1,
                                               unsigned short* __restrict__ h1b, int n) {
    __shared__ float xs[64 * XS_LD];
    __shared__ float ws[32 * WS_LD];
    int tid  = threadIdx.x;
    int row0 = blockIdx.x * 64;
    int tr   = tid >> 4;
    int tc   = tid & 15;

    float acc[4][8];
#pragma unroll
    for (int j = 0; j < 4; j++)
#pragma unroll
        for (int c = 0; c < 8; c++) acc[j][c] = 0.f;

    for (int k0 = 0; k0 < IN_C; k0 += 32) {
        {
            int r  = tid >> 3;
            int c4 = tid & 7;
#pragma unroll
            for (int p = 0; p < 2; p++) {
                int rr = r + p * 32;
                if (row0 + rr < n) {
                    float4 v = *((const float4*)(x + (size_t)(row0 + rr) * IN_C + k0 + c4 * 4));
                    *((float4*)&xs[rr * XS_LD + c4 * 4]) = v;
                }
            }
        }
        {
#pragma unroll
            for (int p = 0; p < 4; p++) {
                int idx = p * 256 + tid;
                int k = idx >> 5, c = idx & 31;
                float4 v = *((const float4*)(W1 + (size_t)(k0 + k) * HID_C + c * 4));
                *((float4*)&ws[k * WS_LD + c * 4]) = v;
            }
        }
        __syncthreads();
#pragma unroll 8
        for (int k = 0; k < 32; k++) {
            float x0 = xs[(tr * 4 + 0) * XS_LD + k];
            float x1 = xs[(tr * 4 + 1) * XS_LD + k];
            float x2 = xs[(tr * 4 + 2) * XS_LD + k];
            float x3 = xs[(tr * 4 + 3) * XS_LD + k];
            float4 wa = *((const float4*)&ws[k * WS_LD + tc * 8]);
            float4 wb = *((const float4*)&ws[k * WS_LD + tc * 8 + 4]);
            acc[0][0] = fmaf(x0, wa.x, acc[0][0]); acc[0][1] = fmaf(x0, wa.y, acc[0][1]);
            acc[0][2] = fmaf(x0, wa.z, acc[0][2]); acc[0][3] = fmaf(x0, wa.w, acc[0][3]);
            acc[0][4] = fmaf(x0, wb.x, acc[0][4]); acc[0][5] = fmaf(x0, wb.y, acc[0][5]);
            acc[0][6] = fmaf(x0, wb.z, acc[0][6]); acc[0][7] = fmaf(x0, wb.w, acc[0][7]);
            acc[1][0] = fmaf(x1, wa.x, acc[1][0]); acc[1][1] = fmaf(x1, wa.y, acc[1][1]);
            acc[1][2] = fmaf(x1, wa.z, acc[1][2]); acc[1][3] = fmaf(x1, wa.w, acc[1][3]);
            acc[1][4] = fmaf(x1, wb.x, acc[1][4]); acc[1][5] = fmaf(x1, wb.y, acc[1][5]);
            acc[1][6] = fmaf(x1, wb.z, acc[1][6]); acc[1][7] = fmaf(x1, wb.w, acc[1][7]);
            acc[2][0] = fmaf(x2, wa.x, acc[2][0]); acc[2][1] = fmaf(x2, wa.y, acc[2][1]);
            acc[2][2] = fmaf(x2, wa.z, acc[2][2]); acc[2][3] = fmaf(x2, wa.w, acc[2][3]);
            acc[2][4] = fmaf(x2, wb.x, acc[2][4]); acc[2][5] = fmaf(x2, wb.y, acc[2][5]);
            acc[2][6] = fmaf(x2, wb.z, acc[2][6]); acc[2][7] = fmaf(x2, wb.w, acc[2][7]);
            acc[3][0] = fmaf(x3, wa.x, acc[3][0]); acc[3][1] = fmaf(x3, wa.y, acc[3][1]);
            acc[3][2] = fmaf(x3, wa.z, acc[3][2]); acc[3][3] = fmaf(x3, wa.w, acc[3][3]);
            acc[3][4] = fmaf(x3, wb.x, acc[3][4]); acc[3][5] = fmaf(x3, wb.y, acc[3][5]);
            acc[3][6] = fmaf(x3, wb.z, acc[3][6]); acc[3][7] = fmaf(x3, wb.w, acc[3][7]);
        }
        __syncthreads();
    }
#pragma unroll
    for (int j = 0; j < 4; j++) {
        int row = row0 + tr * 4 + j;
        if (row < n) {
            uint4 pk;
            pk.x = (unsigned)f2bf(acc[j][0]) | ((unsigned)f2bf(acc[j][1]) << 16);
            pk.y = (unsigned)f2bf(acc[j][2]) | ((unsigned)f2bf(acc[j][3]) << 16);
            pk.z = (unsigned)f2bf(acc[j][4]) | ((unsigned)f2bf(acc[j][5]) << 16);
            pk.w = (unsigned)f2bf(acc[j][6]) | ((unsigned)f2bf(acc[j][7]) << 16);
            *((uint4*)(h1b + (size_t)row * HID_C + tc * 8)) = pk;
        }
    }
}

// ---- layer-1 aggregation: one wave per dst node, bf16 gathers --------------
__global__ __launch_bounds__(256) void k_agg1(const int* __restrict__ rowptr,
                                              const int2* __restrict__ edata,
                                              const unsigned short* __restrict__ h1b,
                                              const float* __restrict__ dinv,
                                              const float* __restrict__ b1,
                                              float* __restrict__ agg1, int n) {
    int wid  = (blockIdx.x * 256 + threadIdx.x) >> 6;   // node id
    int lane = threadIdx.x & 63;                        // owns cols 2*lane, 2*lane+1
    if (wid >= n) return;
    int beg = rowptr[wid], end = rowptr[wid + 1];
    float ax = 0.f, ay = 0.f;
    int j = beg;
    for (; j + 16 <= end; j += 16) {          // 16 outstanding 256B gathers
        int2 e[16];
        unsigned p[16];
#pragma unroll
        for (int q = 0; q < 16; q++) e[q] = edata[j + q];
#pragma unroll
        for (int q = 0; q < 16; q++)
            p[q] = *((const unsigned*)(h1b + (size_t)e[q].x * HID_C) + lane);
#pragma unroll
        for (int q = 0; q < 16; q++) {
            float nm = __int_as_float(e[q].y);
            ax = fmaf(nm, __uint_as_float(p[q] << 16), ax);
            ay = fmaf(nm, __uint_as_float(p[q] & 0xffff0000u), ay);
        }
    }
    for (; j + 4 <= end; j += 4) {
        int2 e[4];
        unsigned p[4];
#pragma unroll
        for (int q = 0; q < 4; q++) e[q] = edata[j + q];
#pragma unroll
        for (int q = 0; q < 4; q++)
            p[q] = *((const unsigned*)(h1b + (size_t)e[q].x * HID_C) + lane);
#pragma unroll
        for (int q = 0; q < 4; q++) {
            float nm = __int_as_float(e[q].y);
            ax = fmaf(nm, __uint_as_float(p[q] << 16), ax);
            ay = fmaf(nm, __uint_as_float(p[q] & 0xffff0000u), ay);
        }
    }
    for (; j < end; j++) {
        int2 e0 = edata[j];
        unsigned p0 = *((const unsigned*)(h1b + (size_t)e0.x * HID_C) + lane);
        float nm = __int_as_float(e0.y);
        ax = fmaf(nm, __uint_as_float(p0 << 16), ax);
        ay = fmaf(nm, __uint_as_float(p0 & 0xffff0000u), ay);
    }
    float di = dinv[wid]; float sc = di * di;
    unsigned ps = *((const unsigned*)(h1b + (size_t)wid * HID_C) + lane);
    float2 bv = ((const float2*)b1)[lane];
    float ox = bv.x + sc * __uint_as_float(ps << 16)        + di * ax;
    float oy = bv.y + sc * __uint_as_float(ps & 0xffff0000u) + di * ay;
    ((float2*)(agg1 + (size_t)wid * HID_C))[lane] = make_float2(ox, oy);
}

// ---- GEMM2: h2[N,2] = relu(agg1) @ W2[128,2] -------------------------------
__global__ __launch_bounds__(256) void k_gemm2(const float* __restrict__ agg1,
                                               const float* __restrict__ W2,
                                               float* __restrict__ h2, int n) {
    int lane = threadIdx.x & 63;
    int wave = threadIdx.x >> 6;
    int node = blockIdx.x * 8 + wave * 2 + (lane >> 5);
    int l = lane & 31;
    float s0 = 0.f, s1 = 0.f;
    if (node < n) {
        float4 v = ((const float4*)(agg1 + (size_t)node * HID_C))[l];
        v.x = fmaxf(v.x, 0.f); v.y = fmaxf(v.y, 0.f);
        v.z = fmaxf(v.z, 0.f); v.w = fmaxf(v.w, 0.f);
        const float2* w2 = (const float2*)W2;
        float2 w0 = w2[l * 4 + 0], w1 = w2[l * 4 + 1];
        float2 wq = w2[l * 4 + 2], w3 = w2[l * 4 + 3];
        s0 = v.x * w0.x + v.y * w1.x + v.z * wq.x + v.w * w3.x;
        s1 = v.x * w0.y + v.y * w1.y + v.z * wq.y + v.w * w3.y;
    }
#pragma unroll
    for (int d = 16; d > 0; d >>= 1) {
        s0 += __shfl_down(s0, d, 32);
        s1 += __shfl_down(s1, d, 32);
    }
    if (node < n && l == 0)
        ((float2*)h2)[node] = make_float2(s0, s1);
}

// ---- layer-2 aggregation: wave per node, lanes over edges ------------------
__global__ __launch_bounds__(256) void k_agg2(const int* __restrict__ rowptr,
                                              const int2* __restrict__ edata,
                                              const float* __restrict__ h2,
                                              const float* __restrict__ dinv,
                                              const float* __restrict__ b2,
                                              float* __restrict__ out, int n) {
    int wid  = (blockIdx.x * 256 + threadIdx.x) >> 6;
    int lane = threadIdx.x & 63;
    if (wid >= n) return;
    int beg = rowptr[wid], end = rowptr[wid + 1];
    float sx = 0.f, sy = 0.f;
    for (int j = beg + lane; j < end; j += 64) {
        int2 ed = edata[j];
        float nm = __int_as_float(ed.y);
        float2 v = ((const float2*)h2)[ed.x];
        sx = fmaf(nm, v.x, sx);
        sy = fmaf(nm, v.y, sy);
    }
#pragma unroll
    for (int d = 32; d > 0; d >>= 1) {
        sx += __shfl_xor(sx, d);
        sy += __shfl_xor(sy, d);
    }
    if (lane == 0) {
        float di = dinv[wid]; float sc = di * di;
        float2 hv = ((const float2*)h2)[wid];
        ((float2*)out)[wid] = make_float2(b2[0] + sc * hv.x + di * sx,
                                          b2[1] + sc * hv.y + di * sy);
    }
}

extern "C" void kernel_launch(void* const* d_in, const int* in_sizes, int n_in,
                              void* d_out, int out_size, void* d_ws, size_t ws_size,
                              hipStream_t stream) {
    const float* x  = (const float*)d_in[0];
    const int*   ei = (const int*)d_in[1];   // [2,E] int32
    const float* ew = (const float*)d_in[2];
    const float* W1 = (const float*)d_in[3];
    const float* b1 = (const float*)d_in[4];
    const float* W2 = (const float*)d_in[5];
    const float* b2 = (const float*)d_in[6];
    float* out = (float*)d_out;

    int N = in_sizes[0] / IN_C;
    int E = in_sizes[2];

    char* ws = (char*)d_ws;
    float* dinv   = (float*)ws; ws += (size_t)N * 4;
    int*   cnt    = (int*)ws;   ws += (size_t)N * 4;
    int*   rowptr = (int*)ws;   ws += (size_t)(N + 1) * 4 + 4;
    int*   cursor = (int*)ws;   ws += (size_t)N * 4;
    int*   bsum   = (int*)ws;   ws += 1024;
    int2*  edata  = (int2*)ws;  ws += (size_t)E * 8;
    unsigned short* h1b = (unsigned short*)ws; ws += (size_t)N * HID_C * 2;
    float* agg1   = (float*)ws; ws += (size_t)N * HID_C * 4;
    float* h2     = (float*)ws; ws += (size_t)N * OUT_C * 4;

    int nb_n = (N + 255) / 256;
    int nb_e = (E + 255) / 256;
    int nb_s = (N + 1023) / 1024;
    int nb_w = (N * 64 + 255) / 256;

    k_zero  <<<nb_n, 256, 0, stream>>>(cnt, N);
    k_hist  <<<nb_e, 256, 0, stream>>>(ei, cnt, E);
    k_scanA <<<nb_s, 256, 0, stream>>>(cnt, rowptr, bsum, N);
    k_scanB <<<1,    256, 0, stream>>>(bsum, nb_s);
    k_scanC <<<nb_n, 256, 0, stream>>>(rowptr, cursor, bsum, N, E);
    k_build <<<nb_e, 256, 0, stream>>>(ei, ew, cursor, edata, E);
    k_degrow<<<nb_n, 256, 0, stream>>>(rowptr, edata, dinv, N);
    k_scale <<<nb_e, 256, 0, stream>>>(edata, dinv, E);
    k_gemm1 <<<(N + 63) / 64, 256, 0, stream>>>(x, W1, h1b, N);
    k_agg1  <<<nb_w, 256, 0, stream>>>(rowptr, edata, h1b, dinv, b1, agg1, N);
    k_gemm2 <<<(N + 7) / 8, 256, 0, stream>>>(agg1, W2, h2, N);
    k_agg2  <<<nb_w, 256, 0, stream>>>(rowptr, edata, h2, dinv, b2, out, N);
}

// Round 6
// 627.630 us; speedup vs baseline: 10.0416x; 1.3665x over previous
//
#include <hip/hip_runtime.h>

#define IN_C  256
#define HID_C 128
#define OUT_C 2
#define BSH   5                    // nodes per bucket = 32
#define NB    32
#define CH    16384                // edges per workgroup in pass 1

__device__ __forceinline__ unsigned short f2bf(float f) {   // RNE float->bf16
    unsigned u = __float_as_uint(f);
    unsigned r = 0x7fffu + ((u >> 16) & 1u);
    return (unsigned short)((u + r) >> 16);
}

// ---- pass 1a: per-wg bucket histogram -> gcnt[b*W + w] ---------------------
__global__ __launch_bounds__(256) void k_count(const int* __restrict__ ei,
                                               int* __restrict__ gcnt,
                                               int E, int K, int W) {
    extern __shared__ int lh[];                // K ints
    int w = blockIdx.x, t = threadIdx.x;
    for (int b = t; b < K; b += 256) lh[b] = 0;
    __syncthreads();
    int j0 = w * CH;
    for (int j = j0 + t; j < j0 + CH && j < E; j += 256)
        atomicAdd(&lh[ei[E + j] >> BSH], 1);
    __syncthreads();
    for (int b = t; b < K; b += 256) gcnt[(size_t)b * W + w] = lh[b];
}

// ---- scan: 4096 elems/block ------------------------------------------------
__global__ __launch_bounds__(256) void k_scanA4(const int* __restrict__ cnt,
                                                int* __restrict__ excl,
                                                int* __restrict__ bsum, int n) {
    __shared__ int ss[256];
    int t = threadIdx.x;
    int base = blockIdx.x * 4096 + t * 16;
    int v[16]; int s = 0;
#pragma unroll
    for (int q = 0; q < 16; q++) { v[q] = (base + q < n) ? cnt[base + q] : 0; s += v[q]; }
    ss[t] = s;
    __syncthreads();
    for (int d = 1; d < 256; d <<= 1) {
        int x = (t >= d) ? ss[t - d] : 0;
        __syncthreads();
        ss[t] += x;
        __syncthreads();
    }
    int pre = (t == 0) ? 0 : ss[t - 1];
    if (t == 255) bsum[blockIdx.x] = ss[255];
    int run = pre;
#pragma unroll
    for (int q = 0; q < 16; q++) { if (base + q < n) excl[base + q] = run; run += v[q]; }
}

__global__ __launch_bounds__(256) void k_scanB(int* __restrict__ bsum, int nb) {
    __shared__ int ss[256];
    int t = threadIdx.x;
    int v = (t < nb) ? bsum[t] : 0;
    ss[t] = v;
    __syncthreads();
    for (int d = 1; d < 256; d <<= 1) {
        int x = (t >= d) ? ss[t - d] : 0;
        __syncthreads();
        ss[t] += x;
        __syncthreads();
    }
    if (t < nb) bsum[t] = ss[t] - v;   // exclusive
}

__global__ void k_scanC4(int* __restrict__ gpos, const int* __restrict__ bsum, int n) {
    int i = blockIdx.x * 256 + threadIdx.x;
    if (i < n) gpos[i] += bsum[i >> 12];
}

// ---- pass 1c: place edges into ebuf, bucket-grouped ------------------------
// ebuf entry: {src | ldst<<17, w}   (src < 2^17, ldst < 32)
__global__ __launch_bounds__(256) void k_place(const int* __restrict__ ei,
                                               const float* __restrict__ w,
                                               const int* __restrict__ gpos,
                                               int2* __restrict__ ebuf,
                                               int E, int K, int W) {
    extern __shared__ int lc[];                // K cursors
    int wg = blockIdx.x, t = threadIdx.x;
    for (int b = t; b < K; b += 256) lc[b] = gpos[(size_t)b * W + wg];
    __syncthreads();
    int j0 = wg * CH;
    for (int j = j0 + t; j < j0 + CH && j < E; j += 256) {
        int s = ei[j], d = ei[E + j];
        float wv = w[j];
        int pos = atomicAdd(&lc[d >> BSH], 1);
        ebuf[pos] = make_int2(s | ((d & (NB - 1)) << 17), __float_as_int(wv));
    }
}

// ---- pass 2: per-bucket fine CSR + deg/dinv (all LDS-local) ----------------
__global__ __launch_bounds__(256) void k_bucket(const int2* __restrict__ ebuf,
                                                const int* __restrict__ gpos,
                                                int2* __restrict__ edata,
                                                int* __restrict__ rowptr,
                                                float* __restrict__ dinv,
                                                int W, int K, int E, int N) {
    __shared__ int lh[NB], lex[NB], lc[NB];
    int b = blockIdx.x, t = threadIdx.x;
    int base = gpos[(size_t)b * W];
    int next = (b + 1 < K) ? gpos[(size_t)(b + 1) * W] : E;
    if (t < NB) lh[t] = 0;
    __syncthreads();
    for (int j = base + t; j < next; j += 256)
        atomicAdd(&lh[(ebuf[j].x >> 17) & (NB - 1)], 1);
    __syncthreads();
    if (t == 0) {
        int run = 0;
        for (int i = 0; i < NB; i++) { lex[i] = run; lc[i] = run; run += lh[i]; }
    }
    __syncthreads();
    if (t < NB) rowptr[b * NB + t] = base + lex[t];
    if (b == K - 1 && t == 0) rowptr[N] = E;
    for (int j = base + t; j < next; j += 256) {
        int2 e = ebuf[j];
        int ld = (e.x >> 17) & (NB - 1);
        int pos = base + atomicAdd(&lc[ld], 1);
        edata[pos] = make_int2(e.x & 0x1FFFF, e.y);
    }
    __syncthreads();
    if (t < NB) {
        int rb = base + lex[t], re = rb + lh[t];
        float s = 1.0f;                         // self-loop weight
        for (int j = rb; j < re; j++) s += __int_as_float(edata[j].y);
        dinv[b * NB + t] = s > 0.f ? rsqrtf(s) : 0.f;
    }
}

// ---- scale edge weights by dinv[src] --------------------------------------
__global__ void k_scale(int2* __restrict__ edata, const float* __restrict__ dinv, int E) {
    int i = blockIdx.x * 256 + threadIdx.x;
    if (i >= E) return;
    int2 e = edata[i];
    e.y = __float_as_int(__int_as_float(e.y) * dinv[e.x]);
    edata[i] = e;
}

// ---- GEMM1: h1b[N,128] (bf16) = x[N,256] @ W1[256,128] ---------------------
#define XS_LD 36
#define WS_LD 132
__global__ __launch_bounds__(256) void k_gemm1(const float* __restrict__ x,
                                               const float* __restrict__ W1,
                                               unsigned short* __restrict__ h1b, int n) {
    __shared__ float xs[64 * XS_LD];
    __shared__ float ws[32 * WS_LD];
    int tid  = threadIdx.x;
    int row0 = blockIdx.x * 64;
    int tr   = tid >> 4;
    int tc   = tid & 15;

    float acc[4][8];
#pragma unroll
    for (int j = 0; j < 4; j++)
#pragma unroll
        for (int c = 0; c < 8; c++) acc[j][c] = 0.f;

    for (int k0 = 0; k0 < IN_C; k0 += 32) {
        {
            int r  = tid >> 3;
            int c4 = tid & 7;
#pragma unroll
            for (int p = 0; p < 2; p++) {
                int rr = r + p * 32;
                if (row0 + rr < n) {
                    float4 v = *((const float4*)(x + (size_t)(row0 + rr) * IN_C + k0 + c4 * 4));
                    *((float4*)&xs[rr * XS_LD + c4 * 4]) = v;
                }
            }
        }
        {
#pragma unroll
            for (int p = 0; p < 4; p++) {
                int idx = p * 256 + tid;
                int k = idx >> 5, c = idx & 31;
                float4 v = *((const float4*)(W1 + (size_t)(k0 + k) * HID_C + c * 4));
                *((float4*)&ws[k * WS_LD + c * 4]) = v;
            }
        }
        __syncthreads();
#pragma unroll 8
        for (int k = 0; k < 32; k++) {
            float x0 = xs[(tr * 4 + 0) * XS_LD + k];
            float x1 = xs[(tr * 4 + 1) * XS_LD + k];
            float x2 = xs[(tr * 4 + 2) * XS_LD + k];
            float x3 = xs[(tr * 4 + 3) * XS_LD + k];
            float4 wa = *((const float4*)&ws[k * WS_LD + tc * 8]);
            float4 wb = *((const float4*)&ws[k * WS_LD + tc * 8 + 4]);
            acc[0][0] = fmaf(x0, wa.x, acc[0][0]); acc[0][1] = fmaf(x0, wa.y, acc[0][1]);
            acc[0][2] = fmaf(x0, wa.z, acc[0][2]); acc[0][3] = fmaf(x0, wa.w, acc[0][3]);
            acc[0][4] = fmaf(x0, wb.x, acc[0][4]); acc[0][5] = fmaf(x0, wb.y, acc[0][5]);
            acc[0][6] = fmaf(x0, wb.z, acc[0][6]); acc[0][7] = fmaf(x0, wb.w, acc[0][7]);
            acc[1][0] = fmaf(x1, wa.x, acc[1][0]); acc[1][1] = fmaf(x1, wa.y, acc[1][1]);
            acc[1][2] = fmaf(x1, wa.z, acc[1][2]); acc[1][3] = fmaf(x1, wa.w, acc[1][3]);
            acc[1][4] = fmaf(x1, wb.x, acc[1][4]); acc[1][5] = fmaf(x1, wb.y, acc[1][5]);
            acc[1][6] = fmaf(x1, wb.z, acc[1][6]); acc[1][7] = fmaf(x1, wb.w, acc[1][7]);
            acc[2][0] = fmaf(x2, wa.x, acc[2][0]); acc[2][1] = fmaf(x2, wa.y, acc[2][1]);
            acc[2][2] = fmaf(x2, wa.z, acc[2][2]); acc[2][3] = fmaf(x2, wa.w, acc[2][3]);
            acc[2][4] = fmaf(x2, wb.x, acc[2][4]); acc[2][5] = fmaf(x2, wb.y, acc[2][5]);
            acc[2][6] = fmaf(x2, wb.z, acc[2][6]); acc[2][7] = fmaf(x2, wb.w, acc[2][7]);
            acc[3][0] = fmaf(x3, wa.x, acc[3][0]); acc[3][1] = fmaf(x3, wa.y, acc[3][1]);
            acc[3][2] = fmaf(x3, wa.z, acc[3][2]); acc[3][3] = fmaf(x3, wa.w, acc[3][3]);
            acc[3][4] = fmaf(x3, wb.x, acc[3][4]); acc[3][5] = fmaf(x3, wb.y, acc[3][5]);
            acc[3][6] = fmaf(x3, wb.z, acc[3][6]); acc[3][7] = fmaf(x3, wb.w, acc[3][7]);
        }
        __syncthreads();
    }
#pragma unroll
    for (int j = 0; j < 4; j++) {
        int row = row0 + tr * 4 + j;
        if (row < n) {
            uint4 pk;
            pk.x = (unsigned)f2bf(acc[j][0]) | ((unsigned)f2bf(acc[j][1]) << 16);
            pk.y = (unsigned)f2bf(acc[j][2]) | ((unsigned)f2bf(acc[j][3]) << 16);
            pk.z = (unsigned)f2bf(acc[j][4]) | ((unsigned)f2bf(acc[j][5]) << 16);
            pk.w = (unsigned)f2bf(acc[j][6]) | ((unsigned)f2bf(acc[j][7]) << 16);
            *((uint4*)(h1b + (size_t)row * HID_C + tc * 8)) = pk;
        }
    }
}

// ---- layer-1 aggregation: one wave per dst node, bf16 gathers --------------
__global__ __launch_bounds__(256) void k_agg1(const int* __restrict__ rowptr,
                                              const int2* __restrict__ edata,
                                              const unsigned short* __restrict__ h1b,
                                              const float* __restrict__ dinv,
                                              const float* __restrict__ b1,
                                              float* __restrict__ agg1, int n) {
    int wid  = (blockIdx.x * 256 + threadIdx.x) >> 6;
    int lane = threadIdx.x & 63;
    if (wid >= n) return;
    int beg = rowptr[wid], end = rowptr[wid + 1];
    float ax = 0.f, ay = 0.f;
    int j = beg;
    for (; j + 16 <= end; j += 16) {
        int2 e[16];
        unsigned p[16];
#pragma unroll
        for (int q = 0; q < 16; q++) e[q] = edata[j + q];
#pragma unroll
        for (int q = 0; q < 16; q++)
            p[q] = *((const unsigned*)(h1b + (size_t)e[q].x * HID_C) + lane);
#pragma unroll
        for (int q = 0; q < 16; q++) {
            float nm = __int_as_float(e[q].y);
            ax = fmaf(nm, __uint_as_float(p[q] << 16), ax);
            ay = fmaf(nm, __uint_as_float(p[q] & 0xffff0000u), ay);
        }
    }
    for (; j + 4 <= end; j += 4) {
        int2 e[4];
        unsigned p[4];
#pragma unroll
        for (int q = 0; q < 4; q++) e[q] = edata[j + q];
#pragma unroll
        for (int q = 0; q < 4; q++)
            p[q] = *((const unsigned*)(h1b + (size_t)e[q].x * HID_C) + lane);
#pragma unroll
        for (int q = 0; q < 4; q++) {
            float nm = __int_as_float(e[q].y);
            ax = fmaf(nm, __uint_as_float(p[q] << 16), ax);
            ay = fmaf(nm, __uint_as_float(p[q] & 0xffff0000u), ay);
        }
    }
    for (; j < end; j++) {
        int2 e0 = edata[j];
        unsigned p0 = *((const unsigned*)(h1b + (size_t)e0.x * HID_C) + lane);
        float nm = __int_as_float(e0.y);
        ax = fmaf(nm, __uint_as_float(p0 << 16), ax);
        ay = fmaf(nm, __uint_as_float(p0 & 0xffff0000u), ay);
    }
    float di = dinv[wid]; float sc = di * di;
    unsigned ps = *((const unsigned*)(h1b + (size_t)wid * HID_C) + lane);
    float2 bv = ((const float2*)b1)[lane];
    float ox = bv.x + sc * __uint_as_float(ps << 16)         + di * ax;
    float oy = bv.y + sc * __uint_as_float(ps & 0xffff0000u) + di * ay;
    ((float2*)(agg1 + (size_t)wid * HID_C))[lane] = make_float2(ox, oy);
}

// ---- GEMM2: h2[N,2] = relu(agg1) @ W2[128,2] -------------------------------
__global__ __launch_bounds__(256) void k_gemm2(const float* __restrict__ agg1,
                                               const float* __restrict__ W2,
                                               float* __restrict__ h2, int n) {
    int lane = threadIdx.x & 63;
    int wave = threadIdx.x >> 6;
    int node = blockIdx.x * 8 + wave * 2 + (lane >> 5);
    int l = lane & 31;
    float s0 = 0.f, s1 = 0.f;
    if (node < n) {
        float4 v = ((const float4*)(agg1 + (size_t)node * HID_C))[l];
        v.x = fmaxf(v.x, 0.f); v.y = fmaxf(v.y, 0.f);
        v.z = fmaxf(v.z, 0.f); v.w = fmaxf(v.w, 0.f);
        const float2* w2 = (const float2*)W2;
        float2 w0 = w2[l * 4 + 0], w1 = w2[l * 4 + 1];
        float2 wq = w2[l * 4 + 2], w3 = w2[l * 4 + 3];
        s0 = v.x * w0.x + v.y * w1.x + v.z * wq.x + v.w * w3.x;
        s1 = v.x * w0.y + v.y * w1.y + v.z * wq.y + v.w * w3.y;
    }
#pragma unroll
    for (int d = 16; d > 0; d >>= 1) {
        s0 += __shfl_down(s0, d, 32);
        s1 += __shfl_down(s1, d, 32);
    }
    if (node < n && l == 0)
        ((float2*)h2)[node] = make_float2(s0, s1);
}

// ---- layer-2 aggregation: wave per node, lanes over edges ------------------
__global__ __launch_bounds__(256) void k_agg2(const int* __restrict__ rowptr,
                                              const int2* __restrict__ edata,
                                              const float* __restrict__ h2,
                                              const float* __restrict__ dinv,
                                              const float* __restrict__ b2,
                                              float* __restrict__ out, int n) {
    int wid  = (blockIdx.x * 256 + threadIdx.x) >> 6;
    int lane = threadIdx.x & 63;
    if (wid >= n) return;
    int beg = rowptr[wid], end = rowptr[wid + 1];
    float sx = 0.f, sy = 0.f;
    for (int j = beg + lane; j < end; j += 64) {
        int2 ed = edata[j];
        float nm = __int_as_float(ed.y);
        float2 v = ((const float2*)h2)[ed.x];
        sx = fmaf(nm, v.x, sx);
        sy = fmaf(nm, v.y, sy);
    }
#pragma unroll
    for (int d = 32; d > 0; d >>= 1) {
        sx += __shfl_xor(sx, d);
        sy += __shfl_xor(sy, d);
    }
    if (lane == 0) {
        float di = dinv[wid]; float sc = di * di;
        float2 hv = ((const float2*)h2)[wid];
        ((float2*)out)[wid] = make_float2(b2[0] + sc * hv.x + di * sx,
                                          b2[1] + sc * hv.y + di * sy);
    }
}

extern "C" void kernel_launch(void* const* d_in, const int* in_sizes, int n_in,
                              void* d_out, int out_size, void* d_ws, size_t ws_size,
                              hipStream_t stream) {
    const float* x  = (const float*)d_in[0];
    const int*   ei = (const int*)d_in[1];   // [2,E] int32
    const float* ew = (const float*)d_in[2];
    const float* W1 = (const float*)d_in[3];
    const float* b1 = (const float*)d_in[4];
    const float* W2 = (const float*)d_in[5];
    const float* b2 = (const float*)d_in[6];
    float* out = (float*)d_out;

    int N = in_sizes[0] / IN_C;
    int E = in_sizes[2];
    int K = (N + NB - 1) >> BSH;             // buckets (N=100000 -> 3125)
    int W = (E + CH - 1) / CH;               // pass-1 workgroups (-> 196)
    int KW = K * W;

    char* ws = (char*)d_ws;
    float* dinv   = (float*)ws; ws += (size_t)N * 4;
    int*   rowptr = (int*)ws;   ws += (size_t)(N + 1) * 4 + 4;
    int*   gcnt   = (int*)ws;   ws += (size_t)KW * 4;
    int*   bsum   = (int*)ws;   ws += 1024;
    int2*  ebuf   = (int2*)ws;  ws += (size_t)E * 8;
    int2*  edata  = (int2*)ws;  ws += (size_t)E * 8;
    unsigned short* h1b = (unsigned short*)ws; ws += (size_t)N * HID_C * 2;
    float* agg1   = (float*)ws; ws += (size_t)N * HID_C * 4;
    float* h2     = (float*)ws; ws += (size_t)N * OUT_C * 4;

    int nb_e  = (E + 255) / 256;
    int nb_s4 = (KW + 4095) / 4096;          // 150 <= 256
    int nb_sc = (KW + 255) / 256;
    int nb_w  = (N * 64 + 255) / 256;
    size_t lds_k = (size_t)K * 4;            // 12.5 KB dynamic LDS

    k_count <<<W, 256, lds_k, stream>>>(ei, gcnt, E, K, W);
    k_scanA4<<<nb_s4, 256, 0, stream>>>(gcnt, gcnt, bsum, KW);   // in-place excl
    k_scanB <<<1, 256, 0, stream>>>(bsum, nb_s4);
    k_scanC4<<<nb_sc, 256, 0, stream>>>(gcnt, bsum, KW);
    k_place <<<W, 256, lds_k, stream>>>(ei, ew, gcnt, ebuf, E, K, W);
    k_bucket<<<K, 256, 0, stream>>>(ebuf, gcnt, edata, rowptr, dinv, W, K, E, N);
    k_scale <<<nb_e, 256, 0, stream>>>(edata, dinv, E);
    k_gemm1 <<<(N + 63) / 64, 256, 0, stream>>>(x, W1, h1b, N);
    k_agg1  <<<nb_w, 256, 0, stream>>>(rowptr, edata, h1b, dinv, b1, agg1, N);
    k_gemm2 <<<(N + 7) / 8, 256, 0, stream>>>(agg1, W2, h2, N);
    k_agg2  <<<nb_w, 256, 0, stream>>>(rowptr, edata, h2, dinv, b2, out, N);
}

// Round 7
// 573.981 us; speedup vs baseline: 10.9802x; 1.0935x over previous
//
#include <hip/hip_runtime.h>

#define IN_C  256
#define HID_C 128
#define OUT_C 2
#define BSH   5                    // nodes per bucket = 32
#define NB    32
#define CH    16384                // edges per workgroup in pass 1
#define BCAP  2048                 // k_bucket LDS edge capacity

typedef __attribute__((ext_vector_type(8))) short short8;
typedef __attribute__((ext_vector_type(4))) float float4v;

__device__ __forceinline__ unsigned short f2bf(float f) {   // RNE float->bf16
    unsigned u = __float_as_uint(f);
    unsigned r = 0x7fffu + ((u >> 16) & 1u);
    return (unsigned short)((u + r) >> 16);
}
__device__ __forceinline__ unsigned pk2(float a, float b) {
    return (unsigned)f2bf(a) | ((unsigned)f2bf(b) << 16);
}

// ---- W1^T bf16 precompute --------------------------------------------------
__global__ void k_wT(const float* __restrict__ W1, unsigned short* __restrict__ w1t) {
    int i = blockIdx.x * 256 + threadIdx.x;     // i = c*256 + k (write-coalesced)
    if (i >= HID_C * IN_C) return;
    int c = i >> 8, k = i & 255;
    w1t[i] = f2bf(W1[(size_t)k * HID_C + c]);
}

// ---- pass 1a: per-wg bucket histogram -> gcnt[b*W + w] ---------------------
__global__ __launch_bounds__(256) void k_count(const int* __restrict__ ei,
                                               int* __restrict__ gcnt,
                                               int E, int K, int W) {
    extern __shared__ int lh[];                // K ints
    int w = blockIdx.x, t = threadIdx.x;
    for (int b = t; b < K; b += 256) lh[b] = 0;
    __syncthreads();
    int j0 = w * CH;
    for (int j = j0 + t; j < j0 + CH && j < E; j += 256)
        atomicAdd(&lh[ei[E + j] >> BSH], 1);
    __syncthreads();
    for (int b = t; b < K; b += 256) gcnt[(size_t)b * W + w] = lh[b];
}

// ---- scan: 4096 elems/block ------------------------------------------------
__global__ __launch_bounds__(256) void k_scanA4(const int* __restrict__ cnt,
                                                int* __restrict__ excl,
                                                int* __restrict__ bsum, int n) {
    __shared__ int ss[256];
    int t = threadIdx.x;
    int base = blockIdx.x * 4096 + t * 16;
    int v[16]; int s = 0;
#pragma unroll
    for (int q = 0; q < 16; q++) { v[q] = (base + q < n) ? cnt[base + q] : 0; s += v[q]; }
    ss[t] = s;
    __syncthreads();
    for (int d = 1; d < 256; d <<= 1) {
        int x = (t >= d) ? ss[t - d] : 0;
        __syncthreads();
        ss[t] += x;
        __syncthreads();
    }
    int pre = (t == 0) ? 0 : ss[t - 1];
    if (t == 255) bsum[blockIdx.x] = ss[255];
    int run = pre;
#pragma unroll
    for (int q = 0; q < 16; q++) { if (base + q < n) excl[base + q] = run; run += v[q]; }
}

__global__ __launch_bounds__(256) void k_scanB(int* __restrict__ bsum, int nb) {
    __shared__ int ss[256];
    int t = threadIdx.x;
    int v = (t < nb) ? bsum[t] : 0;
    ss[t] = v;
    __syncthreads();
    for (int d = 1; d < 256; d <<= 1) {
        int x = (t >= d) ? ss[t - d] : 0;
        __syncthreads();
        ss[t] += x;
        __syncthreads();
    }
    if (t < nb) bsum[t] = ss[t] - v;   // exclusive
}

__global__ void k_scanC4(int* __restrict__ gpos, const int* __restrict__ bsum, int n) {
    int i = blockIdx.x * 256 + threadIdx.x;
    if (i < n) gpos[i] += bsum[i >> 12];
}

// ---- pass 1c: place edges into ebuf, bucket-grouped ------------------------
// ebuf entry: {src | ldst<<17, w}   (src < 2^17, ldst < 32)
__global__ __launch_bounds__(256) void k_place(const int* __restrict__ ei,
                                               const float* __restrict__ w,
                                               const int* __restrict__ gpos,
                                               int2* __restrict__ ebuf,
                                               int E, int K, int W) {
    extern __shared__ int lc[];                // K cursors
    int wg = blockIdx.x, t = threadIdx.x;
    for (int b = t; b < K; b += 256) lc[b] = gpos[(size_t)b * W + wg];
    __syncthreads();
    int j0 = wg * CH;
    for (int j = j0 + t; j < j0 + CH && j < E; j += 256) {
        int s = ei[j], d = ei[E + j];
        float wv = w[j];
        int pos = atomicAdd(&lc[d >> BSH], 1);
        ebuf[pos] = make_int2(s | ((d & (NB - 1)) << 17), __float_as_int(wv));
    }
}

// ---- pass 2: per-bucket fine CSR + dinv, single ebuf read, LDS sort --------
__global__ __launch_bounds__(256) void k_bucket(const int2* __restrict__ ebuf,
                                                const int* __restrict__ gpos,
                                                int2* __restrict__ edata,
                                                int* __restrict__ rowptr,
                                                float* __restrict__ dinv,
                                                int W, int K, int E, int N) {
    __shared__ int2 le[BCAP], ls[BCAP];
    __shared__ int lh[NB], lex[NB], lc[NB];
    int b = blockIdx.x, t = threadIdx.x;
    int base = gpos[(size_t)b * W];
    int next = (b + 1 < K) ? gpos[(size_t)(b + 1) * W] : E;
    int cnt = next - base;
    if (t < NB) lh[t] = 0;
    __syncthreads();
    if (cnt <= BCAP) {
        for (int j = t; j < cnt; j += 256) {
            int2 e = ebuf[base + j];
            le[j] = e;
            atomicAdd(&lh[(e.x >> 17) & (NB - 1)], 1);
        }
        __syncthreads();
        if (t == 0) {
            int run = 0;
            for (int i = 0; i < NB; i++) { lex[i] = run; lc[i] = run; run += lh[i]; }
        }
        __syncthreads();
        for (int j = t; j < cnt; j += 256) {
            int2 e = le[j];
            int pos = atomicAdd(&lc[(e.x >> 17) & (NB - 1)], 1);
            ls[pos] = make_int2(e.x & 0x1FFFF, e.y);
        }
        __syncthreads();
        for (int j = t; j < cnt; j += 256) edata[base + j] = ls[j];   // coalesced
        if (t < NB) {
            int node = b * NB + t;
            if (node < N) {
                rowptr[node] = base + lex[t];
                float s = 1.0f;                      // self-loop weight
                int rb = lex[t], re = rb + lh[t];
                for (int j = rb; j < re; j++) s += __int_as_float(ls[j].y);
                dinv[node] = s > 0.f ? rsqrtf(s) : 0.f;
            }
        }
    } else {                                         // fallback (never at E/N=32)
        for (int j = base + t; j < next; j += 256)
            atomicAdd(&lh[(ebuf[j].x >> 17) & (NB - 1)], 1);
        __syncthreads();
        if (t == 0) {
            int run = 0;
            for (int i = 0; i < NB; i++) { lex[i] = run; lc[i] = run; run += lh[i]; }
        }
        __syncthreads();
        for (int j = base + t; j < next; j += 256) {
            int2 e = ebuf[j];
            int pos = base + atomicAdd(&lc[(e.x >> 17) & (NB - 1)], 1);
            edata[pos] = make_int2(e.x & 0x1FFFF, e.y);
        }
        __syncthreads();
        if (t < NB) {
            int node = b * NB + t;
            if (node < N) {
                int rb = base + lex[t], re = rb + lh[t];
                rowptr[node] = rb;
                float s = 1.0f;
                for (int j = rb; j < re; j++) s += __int_as_float(edata[j].y);
                dinv[node] = s > 0.f ? rsqrtf(s) : 0.f;
            }
        }
    }
    if (b == K - 1 && t == 0) rowptr[N] = E;
}

// ---- GEMM1 (MFMA bf16): h1b[N,128] = x[N,256] @ W1 -------------------------
#define XS_LD 36           // bf16 units/row (72 B, 2-way-bank pattern)
#define WT_LD 260          // bf16 units/col-row (520 B)
__global__ __launch_bounds__(256) void k_gemm1(const float* __restrict__ x,
                                               const unsigned short* __restrict__ w1t,
                                               unsigned short* __restrict__ h1b, int n) {
    __shared__ __align__(16) unsigned short wt[HID_C * WT_LD];   // 66560 B
    __shared__ __align__(16) unsigned short xs[64 * XS_LD];      // 4608 B
    int tid  = threadIdx.x;
    int row0 = blockIdx.x * 64;
    // stage whole W1T (bf16, 64 KB) once
    for (int it = 0; it < 16; it++) {
        int idx = it * 256 + tid;               // 16B-chunk id
        int c = idx >> 5, kc = idx & 31;
        uint4 v = *(const uint4*)(w1t + (size_t)c * IN_C + kc * 8);
        uint2* dst = (uint2*)(wt + c * WT_LD + kc * 8);
        dst[0] = make_uint2(v.x, v.y);
        dst[1] = make_uint2(v.z, v.w);
    }
    int wv = tid >> 6, ln = tid & 63;
    int m = ln & 15, quad = ln >> 4;
    float4v acc[8];
#pragma unroll
    for (int ct = 0; ct < 8; ct++) acc[ct] = (float4v){0.f, 0.f, 0.f, 0.f};

    for (int k0 = 0; k0 < IN_C; k0 += 32) {
        __syncthreads();                         // protect xs from prev iter readers
        {   // stage x tile -> bf16 LDS (64 rows x 32 k)
            int r = tid >> 2, s4 = tid & 3;
            int gr = row0 + r; if (gr >= n) gr = n - 1;
            const float4* px = (const float4*)(x + (size_t)gr * IN_C + k0 + s4 * 8);
            float4 a = px[0], bq = px[1];
            uint2* d = (uint2*)(xs + r * XS_LD + s4 * 8);
            d[0] = make_uint2(pk2(a.x, a.y), pk2(a.z, a.w));
            d[1] = make_uint2(pk2(bq.x, bq.y), pk2(bq.z, bq.w));
        }
        __syncthreads();
        union { uint2 u[2]; short8 v; } af;
        const uint2* pa = (const uint2*)(xs + (wv * 16 + m) * XS_LD + quad * 8);
        af.u[0] = pa[0]; af.u[1] = pa[1];
#pragma unroll
        for (int ct = 0; ct < 8; ct++) {
            union { uint2 u[2]; short8 v; } bf;
            const uint2* pb = (const uint2*)(wt + (ct * 16 + m) * WT_LD + k0 + quad * 8);
            bf.u[0] = pb[0]; bf.u[1] = pb[1];
            acc[ct] = __builtin_amdgcn_mfma_f32_16x16x32_bf16(af.v, bf.v, acc[ct], 0, 0, 0);
        }
    }
    __syncthreads();
    // epilogue: scatter acc -> LDS tile (reuse wt), then coalesced store
    unsigned short* ot = wt;                     // 64 rows x 136 stride (272 B)
#pragma unroll
    for (int ct = 0; ct < 8; ct++)
#pragma unroll
        for (int r = 0; r < 4; r++)
            ot[(wv * 16 + quad * 4 + r) * 136 + ct * 16 + m] = f2bf(acc[ct][r]);
    __syncthreads();
#pragma unroll
    for (int p = 0; p < 4; p++) {
        int idx = p * 256 + tid;                 // 16B chunk, 0..1023
        int r = idx >> 4, c8 = idx & 15;
        if (row0 + r < n)
            *(uint4*)(h1b + (size_t)(row0 + r) * HID_C + c8 * 8) =
                *(const uint4*)(ot + r * 136 + c8 * 8);
    }
}

// ---- layer-1 aggregation: wave/node, bf16 gathers, fused dinv[src] ---------
__global__ __launch_bounds__(256) void k_agg1(const int* __restrict__ rowptr,
                                              const int2* __restrict__ edata,
                                              const unsigned short* __restrict__ h1b,
                                              const float* __restrict__ dinv,
                                              const float* __restrict__ b1,
                                              float* __restrict__ agg1, int n) {
    int wid  = (blockIdx.x * 256 + threadIdx.x) >> 6;
    int lane = threadIdx.x & 63;
    if (wid >= n) return;
    int beg = rowptr[wid], end = rowptr[wid + 1];
    float ax = 0.f, ay = 0.f;
    int j = beg;
    for (; j + 16 <= end; j += 16) {
        int2 e[16];
        unsigned p[16];
#pragma unroll
        for (int q = 0; q < 16; q++) e[q] = edata[j + q];
#pragma unroll
        for (int q = 0; q < 16; q++)
            p[q] = *((const unsigned*)(h1b + (size_t)e[q].x * HID_C) + lane);
#pragma unroll
        for (int q = 0; q < 16; q++) {
            float nm = __int_as_float(e[q].y) * dinv[e[q].x];
            ax = fmaf(nm, __uint_as_float(p[q] << 16), ax);
            ay = fmaf(nm, __uint_as_float(p[q] & 0xffff0000u), ay);
        }
    }
    for (; j + 4 <= end; j += 4) {
        int2 e[4];
        unsigned p[4];
#pragma unroll
        for (int q = 0; q < 4; q++) e[q] = edata[j + q];
#pragma unroll
        for (int q = 0; q < 4; q++)
            p[q] = *((const unsigned*)(h1b + (size_t)e[q].x * HID_C) + lane);
#pragma unroll
        for (int q = 0; q < 4; q++) {
            float nm = __int_as_float(e[q].y) * dinv[e[q].x];
            ax = fmaf(nm, __uint_as_float(p[q] << 16), ax);
            ay = fmaf(nm, __uint_as_float(p[q] & 0xffff0000u), ay);
        }
    }
    for (; j < end; j++) {
        int2 e0 = edata[j];
        unsigned p0 = *((const unsigned*)(h1b + (size_t)e0.x * HID_C) + lane);
        float nm = __int_as_float(e0.y) * dinv[e0.x];
        ax = fmaf(nm, __uint_as_float(p0 << 16), ax);
        ay = fmaf(nm, __uint_as_float(p0 & 0xffff0000u), ay);
    }
    float di = dinv[wid]; float sc = di * di;
    unsigned ps = *((const unsigned*)(h1b + (size_t)wid * HID_C) + lane);
    float2 bv = ((const float2*)b1)[lane];
    float ox = bv.x + sc * __uint_as_float(ps << 16)         + di * ax;
    float oy = bv.y + sc * __uint_as_float(ps & 0xffff0000u) + di * ay;
    ((float2*)(agg1 + (size_t)wid * HID_C))[lane] = make_float2(ox, oy);
}

// ---- GEMM2: h2[N,2] = relu(agg1) @ W2[128,2] -------------------------------
__global__ __launch_bounds__(256) void k_gemm2(const float* __restrict__ agg1,
                                               const float* __restrict__ W2,
                                               float* __restrict__ h2, int n) {
    int lane = threadIdx.x & 63;
    int wave = threadIdx.x >> 6;
    int node = blockIdx.x * 8 + wave * 2 + (lane >> 5);
    int l = lane & 31;
    float s0 = 0.f, s1 = 0.f;
    if (node < n) {
        float4 v = ((const float4*)(agg1 + (size_t)node * HID_C))[l];
        v.x = fmaxf(v.x, 0.f); v.y = fmaxf(v.y, 0.f);
        v.z = fmaxf(v.z, 0.f); v.w = fmaxf(v.w, 0.f);
        const float2* w2 = (const float2*)W2;
        float2 w0 = w2[l * 4 + 0], w1 = w2[l * 4 + 1];
        float2 wq = w2[l * 4 + 2], w3 = w2[l * 4 + 3];
        s0 = v.x * w0.x + v.y * w1.x + v.z * wq.x + v.w * w3.x;
        s1 = v.x * w0.y + v.y * w1.y + v.z * wq.y + v.w * w3.y;
    }
#pragma unroll
    for (int d = 16; d > 0; d >>= 1) {
        s0 += __shfl_down(s0, d, 32);
        s1 += __shfl_down(s1, d, 32);
    }
    if (node < n && l == 0)
        ((float2*)h2)[node] = make_float2(s0, s1);
}

// ---- layer-2 aggregation: wave/node, lanes over edges, fused dinv[src] -----
__global__ __launch_bounds__(256) void k_agg2(const int* __restrict__ rowptr,
                                              const int2* __restrict__ edata,
                                              const float* __restrict__ h2,
                                              const float* __restrict__ dinv,
                                              const float* __restrict__ b2,
                                              float* __restrict__ out, int n) {
    int wid  = (blockIdx.x * 256 + threadIdx.x) >> 6;
    int lane = threadIdx.x & 63;
    if (wid >= n) return;
    int beg = rowptr[wid], end = rowptr[wid + 1];
    float sx = 0.f, sy = 0.f;
    for (int j = beg + lane; j < end; j += 64) {
        int2 ed = edata[j];
        float nm = __int_as_float(ed.y) * dinv[ed.x];
        float2 v = ((const float2*)h2)[ed.x];
        sx = fmaf(nm, v.x, sx);
        sy = fmaf(nm, v.y, sy);
    }
#pragma unroll
    for (int d = 32; d > 0; d >>= 1) {
        sx += __shfl_xor(sx, d);
        sy += __shfl_xor(sy, d);
    }
    if (lane == 0) {
        float di = dinv[wid]; float sc = di * di;
        float2 hv = ((const float2*)h2)[wid];
        ((float2*)out)[wid] = make_float2(b2[0] + sc * hv.x + di * sx,
                                          b2[1] + sc * hv.y + di * sy);
    }
}

extern "C" void kernel_launch(void* const* d_in, const int* in_sizes, int n_in,
                              void* d_out, int out_size, void* d_ws, size_t ws_size,
                              hipStream_t stream) {
    const float* x  = (const float*)d_in[0];
    const int*   ei = (const int*)d_in[1];   // [2,E] int32
    const float* ew = (const float*)d_in[2];
    const float* W1 = (const float*)d_in[3];
    const float* b1 = (const float*)d_in[4];
    const float* W2 = (const float*)d_in[5];
    const float* b2 = (const float*)d_in[6];
    float* out = (float*)d_out;

    int N = in_sizes[0] / IN_C;
    int E = in_sizes[2];
    int K = (N + NB - 1) >> BSH;             // buckets (3125)
    int W = (E + CH - 1) / CH;               // pass-1 workgroups (196)
    int KW = K * W;

    char* ws = (char*)d_ws;
    float* dinv   = (float*)ws; ws += (size_t)N * 4;
    int*   rowptr = (int*)ws;   ws += (size_t)(N + 1) * 4 + 4;
    int*   gcnt   = (int*)ws;   ws += (size_t)KW * 4;
    int*   bsum   = (int*)ws;   ws += 1024;
    int2*  ebuf   = (int2*)ws;  ws += (size_t)E * 8;
    int2*  edata  = (int2*)ws;  ws += (size_t)E * 8;
    unsigned short* w1t = (unsigned short*)ws; ws += (size_t)HID_C * IN_C * 2;
    unsigned short* h1b = (unsigned short*)ws; ws += (size_t)N * HID_C * 2;
    float* agg1   = (float*)ws; ws += (size_t)N * HID_C * 4;
    float* h2     = (float*)ws; ws += (size_t)N * OUT_C * 4;

    int nb_s4 = (KW + 4095) / 4096;
    int nb_sc = (KW + 255) / 256;
    int nb_w  = (N * 64 + 255) / 256;
    size_t lds_k = (size_t)K * 4;            // 12.5 KB dynamic LDS

    k_wT    <<<(HID_C * IN_C + 255) / 256, 256, 0, stream>>>(W1, w1t);
    k_count <<<W, 256, lds_k, stream>>>(ei, gcnt, E, K, W);
    k_scanA4<<<nb_s4, 256, 0, stream>>>(gcnt, gcnt, bsum, KW);
    k_scanB <<<1, 256, 0, stream>>>(bsum, nb_s4);
    k_scanC4<<<nb_sc, 256, 0, stream>>>(gcnt, bsum, KW);
    k_place <<<W, 256, lds_k, stream>>>(ei, ew, gcnt, ebuf, E, K, W);
    k_bucket<<<K, 256, 0, stream>>>(ebuf, gcnt, edata, rowptr, dinv, W, K, E, N);
    k_gemm1 <<<(N + 63) / 64, 256, 0, stream>>>(x, w1t, h1b, N);
    k_agg1  <<<nb_w, 256, 0, stream>>>(rowptr, edata, h1b, dinv, b1, agg1, N);
    k_gemm2 <<<(N + 7) / 8, 256, 0, stream>>>(agg1, W2, h2, N);
    k_agg2  <<<nb_w, 256, 0, stream>>>(rowptr, edata, h2, dinv, b2, out, N);
}

// Round 8
// 573.158 us; speedup vs baseline: 10.9959x; 1.0014x over previous
//
#include <hip/hip_runtime.h>

#define IN_C  256
#define HID_C 128
#define OUT_C 2
#define BSH   5                    // nodes per bucket = 32
#define NB    32
#define CH    16384                // edges per workgroup in pass 1
#define BCAP  2048                 // k_bucket LDS edge capacity

typedef __attribute__((ext_vector_type(8))) short short8;
typedef __attribute__((ext_vector_type(4))) float float4v;

__device__ __forceinline__ unsigned short f2bf(float f) {   // RNE float->bf16
    unsigned u = __float_as_uint(f);
    unsigned r = 0x7fffu + ((u >> 16) & 1u);
    return (unsigned short)((u + r) >> 16);
}
__device__ __forceinline__ unsigned pk2(float a, float b) {
    return (unsigned)f2bf(a) | ((unsigned)f2bf(b) << 16);
}
__device__ __forceinline__ void ntld_edge(const int2* p, int& s, float& w) {
    long long raw = __builtin_nontemporal_load((const long long*)p);
    s = (int)(unsigned)(raw & 0xffffffffll);
    int wb = (int)(raw >> 32);
    w = __int_as_float(wb);
}

// ---- W1^T bf16 precompute --------------------------------------------------
__global__ void k_wT(const float* __restrict__ W1, unsigned short* __restrict__ w1t) {
    int i = blockIdx.x * 256 + threadIdx.x;     // i = c*256 + k (write-coalesced)
    if (i >= HID_C * IN_C) return;
    int c = i >> 8, k = i & 255;
    w1t[i] = f2bf(W1[(size_t)k * HID_C + c]);
}

// ---- pass 1a: per-wg bucket histogram -> gcnt[b*W + w] ---------------------
__global__ __launch_bounds__(256) void k_count(const int* __restrict__ ei,
                                               int* __restrict__ gcnt,
                                               int E, int K, int W) {
    extern __shared__ int lh[];                // K ints
    int w = blockIdx.x, t = threadIdx.x;
    for (int b = t; b < K; b += 256) lh[b] = 0;
    __syncthreads();
    int j0 = w * CH;
    for (int j = j0 + t; j < j0 + CH && j < E; j += 256)
        atomicAdd(&lh[ei[E + j] >> BSH], 1);
    __syncthreads();
    for (int b = t; b < K; b += 256) gcnt[(size_t)b * W + w] = lh[b];
}

// ---- scan: 4096 elems/block ------------------------------------------------
__global__ __launch_bounds__(256) void k_scanA4(const int* __restrict__ cnt,
                                                int* __restrict__ excl,
                                                int* __restrict__ bsum, int n) {
    __shared__ int ss[256];
    int t = threadIdx.x;
    int base = blockIdx.x * 4096 + t * 16;
    int v[16]; int s = 0;
#pragma unroll
    for (int q = 0; q < 16; q++) { v[q] = (base + q < n) ? cnt[base + q] : 0; s += v[q]; }
    ss[t] = s;
    __syncthreads();
    for (int d = 1; d < 256; d <<= 1) {
        int x = (t >= d) ? ss[t - d] : 0;
        __syncthreads();
        ss[t] += x;
        __syncthreads();
    }
    int pre = (t == 0) ? 0 : ss[t - 1];
    if (t == 255) bsum[blockIdx.x] = ss[255];
    int run = pre;
#pragma unroll
    for (int q = 0; q < 16; q++) { if (base + q < n) excl[base + q] = run; run += v[q]; }
}

__global__ __launch_bounds__(256) void k_scanB(int* __restrict__ bsum, int nb) {
    __shared__ int ss[256];
    int t = threadIdx.x;
    int v = (t < nb) ? bsum[t] : 0;
    ss[t] = v;
    __syncthreads();
    for (int d = 1; d < 256; d <<= 1) {
        int x = (t >= d) ? ss[t - d] : 0;
        __syncthreads();
        ss[t] += x;
        __syncthreads();
    }
    if (t < nb) bsum[t] = ss[t] - v;   // exclusive
}

__global__ void k_scanC4(int* __restrict__ gpos, const int* __restrict__ bsum, int n) {
    int i = blockIdx.x * 256 + threadIdx.x;
    if (i < n) gpos[i] += bsum[i >> 12];
}

// ---- pass 1c: place edges into ebuf, bucket-grouped ------------------------
// ebuf entry: {src | ldst<<17, w}   (src < 2^17, ldst < 32)
__global__ __launch_bounds__(256) void k_place(const int* __restrict__ ei,
                                               const float* __restrict__ w,
                                               const int* __restrict__ gpos,
                                               int2* __restrict__ ebuf,
                                               int E, int K, int W) {
    extern __shared__ int lc[];                // K cursors
    int wg = blockIdx.x, t = threadIdx.x;
    for (int b = t; b < K; b += 256) lc[b] = gpos[(size_t)b * W + wg];
    __syncthreads();
    int j0 = wg * CH;
    for (int j = j0 + t; j < j0 + CH && j < E; j += 256) {
        int s = ei[j], d = ei[E + j];
        float wv = w[j];
        int pos = atomicAdd(&lc[d >> BSH], 1);
        ebuf[pos] = make_int2(s | ((d & (NB - 1)) << 17), __float_as_int(wv));
    }
}

// ---- pass 2: per-bucket fine CSR + dinv, single ebuf read, LDS sort --------
__global__ __launch_bounds__(256) void k_bucket(const int2* __restrict__ ebuf,
                                                const int* __restrict__ gpos,
                                                int2* __restrict__ edata,
                                                int* __restrict__ rowptr,
                                                float* __restrict__ dinv,
                                                int W, int K, int E, int N) {
    __shared__ int2 le[BCAP], ls[BCAP];
    __shared__ int lh[NB], lex[NB], lc[NB];
    int b = blockIdx.x, t = threadIdx.x;
    int base = gpos[(size_t)b * W];
    int next = (b + 1 < K) ? gpos[(size_t)(b + 1) * W] : E;
    int cnt = next - base;
    if (t < NB) lh[t] = 0;
    __syncthreads();
    if (cnt <= BCAP) {
        for (int j = t; j < cnt; j += 256) {
            int2 e = ebuf[base + j];
            le[j] = e;
            atomicAdd(&lh[(e.x >> 17) & (NB - 1)], 1);
        }
        __syncthreads();
        if (t == 0) {
            int run = 0;
            for (int i = 0; i < NB; i++) { lex[i] = run; lc[i] = run; run += lh[i]; }
        }
        __syncthreads();
        for (int j = t; j < cnt; j += 256) {
            int2 e = le[j];
            int pos = atomicAdd(&lc[(e.x >> 17) & (NB - 1)], 1);
            ls[pos] = make_int2(e.x & 0x1FFFF, e.y);
        }
        __syncthreads();
        for (int j = t; j < cnt; j += 256) edata[base + j] = ls[j];   // coalesced
        if (t < NB) {
            int node = b * NB + t;
            if (node < N) {
                rowptr[node] = base + lex[t];
                float s = 1.0f;                      // self-loop weight
                int rb = lex[t], re = rb + lh[t];
                for (int j = rb; j < re; j++) s += __int_as_float(ls[j].y);
                dinv[node] = s > 0.f ? rsqrtf(s) : 0.f;
            }
        }
    } else {                                         // fallback (never at E/N=32)
        for (int j = base + t; j < next; j += 256)
            atomicAdd(&lh[(ebuf[j].x >> 17) & (NB - 1)], 1);
        __syncthreads();
        if (t == 0) {
            int run = 0;
            for (int i = 0; i < NB; i++) { lex[i] = run; lc[i] = run; run += lh[i]; }
        }
        __syncthreads();
        for (int j = base + t; j < next; j += 256) {
            int2 e = ebuf[j];
            int pos = base + atomicAdd(&lc[(e.x >> 17) & (NB - 1)], 1);
            edata[pos] = make_int2(e.x & 0x1FFFF, e.y);
        }
        __syncthreads();
        if (t < NB) {
            int node = b * NB + t;
            if (node < N) {
                int rb = base + lex[t], re = rb + lh[t];
                rowptr[node] = rb;
                float s = 1.0f;
                for (int j = rb; j < re; j++) s += __int_as_float(edata[j].y);
                dinv[node] = s > 0.f ? rsqrtf(s) : 0.f;
            }
        }
    }
    if (b == K - 1 && t == 0) rowptr[N] = E;
}

// ---- scale edge weights by dinv[src] (restored — pre-scale off the hot loop)
__global__ void k_scale(int2* __restrict__ edata, const float* __restrict__ dinv, int E) {
    int i = blockIdx.x * 256 + threadIdx.x;
    if (i >= E) return;
    int2 e = edata[i];
    e.y = __float_as_int(__int_as_float(e.y) * dinv[e.x]);
    edata[i] = e;
}

// ---- GEMM1 (MFMA bf16): h1b[N,128] = x[N,256] @ W1 -------------------------
#define XS_LD 36
#define WT_LD 260
__global__ __launch_bounds__(256) void k_gemm1(const float* __restrict__ x,
                                               const unsigned short* __restrict__ w1t,
                                               unsigned short* __restrict__ h1b, int n) {
    __shared__ __align__(16) unsigned short wt[HID_C * WT_LD];
    __shared__ __align__(16) unsigned short xs[64 * XS_LD];
    int tid  = threadIdx.x;
    int row0 = blockIdx.x * 64;
    for (int it = 0; it < 16; it++) {
        int idx = it * 256 + tid;
        int c = idx >> 5, kc = idx & 31;
        uint4 v = *(const uint4*)(w1t + (size_t)c * IN_C + kc * 8);
        uint2* dst = (uint2*)(wt + c * WT_LD + kc * 8);
        dst[0] = make_uint2(v.x, v.y);
        dst[1] = make_uint2(v.z, v.w);
    }
    int wv = tid >> 6, ln = tid & 63;
    int m = ln & 15, quad = ln >> 4;
    float4v acc[8];
#pragma unroll
    for (int ct = 0; ct < 8; ct++) acc[ct] = (float4v){0.f, 0.f, 0.f, 0.f};

    for (int k0 = 0; k0 < IN_C; k0 += 32) {
        __syncthreads();
        {
            int r = tid >> 2, s4 = tid & 3;
            int gr = row0 + r; if (gr >= n) gr = n - 1;
            const float4* px = (const float4*)(x + (size_t)gr * IN_C + k0 + s4 * 8);
            float4 a = px[0], bq = px[1];
            uint2* d = (uint2*)(xs + r * XS_LD + s4 * 8);
            d[0] = make_uint2(pk2(a.x, a.y), pk2(a.z, a.w));
            d[1] = make_uint2(pk2(bq.x, bq.y), pk2(bq.z, bq.w));
        }
        __syncthreads();
        union { uint2 u[2]; short8 v; } af;
        const uint2* pa = (const uint2*)(xs + (wv * 16 + m) * XS_LD + quad * 8);
        af.u[0] = pa[0]; af.u[1] = pa[1];
#pragma unroll
        for (int ct = 0; ct < 8; ct++) {
            union { uint2 u[2]; short8 v; } bf;
            const uint2* pb = (const uint2*)(wt + (ct * 16 + m) * WT_LD + k0 + quad * 8);
            bf.u[0] = pb[0]; bf.u[1] = pb[1];
            acc[ct] = __builtin_amdgcn_mfma_f32_16x16x32_bf16(af.v, bf.v, acc[ct], 0, 0, 0);
        }
    }
    __syncthreads();
    unsigned short* ot = wt;
#pragma unroll
    for (int ct = 0; ct < 8; ct++)
#pragma unroll
        for (int r = 0; r < 4; r++)
            ot[(wv * 16 + quad * 4 + r) * 136 + ct * 16 + m] = f2bf(acc[ct][r]);
    __syncthreads();
#pragma unroll
    for (int p = 0; p < 4; p++) {
        int idx = p * 256 + tid;
        int r = idx >> 4, c8 = idx & 15;
        if (row0 + r < n)
            *(uint4*)(h1b + (size_t)(row0 + r) * HID_C + c8 * 8) =
                *(const uint4*)(ot + r * 136 + c8 * 8);
    }
}

// ---- layer-1 aggregation: wave/node, bf16 gathers, nontemporal edata -------
__global__ __launch_bounds__(256) void k_agg1(const int* __restrict__ rowptr,
                                              const int2* __restrict__ edata,
                                              const unsigned short* __restrict__ h1b,
                                              const float* __restrict__ dinv,
                                              const float* __restrict__ b1,
                                              float* __restrict__ agg1, int n) {
    int wid  = (blockIdx.x * 256 + threadIdx.x) >> 6;
    int lane = threadIdx.x & 63;
    if (wid >= n) return;
    int beg = rowptr[wid], end = rowptr[wid + 1];
    float ax = 0.f, ay = 0.f;
    int j = beg;
    for (; j + 16 <= end; j += 16) {
        int   es[16]; float ew[16];
        unsigned p[16];
#pragma unroll
        for (int q = 0; q < 16; q++) ntld_edge(&edata[j + q], es[q], ew[q]);
#pragma unroll
        for (int q = 0; q < 16; q++)
            p[q] = *((const unsigned*)(h1b + (size_t)es[q] * HID_C) + lane);
#pragma unroll
        for (int q = 0; q < 16; q++) {
            ax = fmaf(ew[q], __uint_as_float(p[q] << 16), ax);
            ay = fmaf(ew[q], __uint_as_float(p[q] & 0xffff0000u), ay);
        }
    }
    for (; j + 4 <= end; j += 4) {
        int   es[4]; float ew[4];
        unsigned p[4];
#pragma unroll
        for (int q = 0; q < 4; q++) ntld_edge(&edata[j + q], es[q], ew[q]);
#pragma unroll
        for (int q = 0; q < 4; q++)
            p[q] = *((const unsigned*)(h1b + (size_t)es[q] * HID_C) + lane);
#pragma unroll
        for (int q = 0; q < 4; q++) {
            ax = fmaf(ew[q], __uint_as_float(p[q] << 16), ax);
            ay = fmaf(ew[q], __uint_as_float(p[q] & 0xffff0000u), ay);
        }
    }
    for (; j < end; j++) {
        int es; float ewv;
        ntld_edge(&edata[j], es, ewv);
        unsigned p0 = *((const unsigned*)(h1b + (size_t)es * HID_C) + lane);
        ax = fmaf(ewv, __uint_as_float(p0 << 16), ax);
        ay = fmaf(ewv, __uint_as_float(p0 & 0xffff0000u), ay);
    }
    float di = dinv[wid]; float sc = di * di;
    unsigned ps = *((const unsigned*)(h1b + (size_t)wid * HID_C) + lane);
    float2 bv = ((const float2*)b1)[lane];
    float2 o = make_float2(bv.x + sc * __uint_as_float(ps << 16)         + di * ax,
                           bv.y + sc * __uint_as_float(ps & 0xffff0000u) + di * ay);
    __builtin_nontemporal_store(*(const double*)&o,
                                (double*)(agg1 + (size_t)wid * HID_C) + lane);
}

// ---- GEMM2: h2[N,2] = relu(agg1) @ W2[128,2] -------------------------------
__global__ __launch_bounds__(256) void k_gemm2(const float* __restrict__ agg1,
                                               const float* __restrict__ W2,
                                               float* __restrict__ h2, int n) {
    int lane = threadIdx.x & 63;
    int wave = threadIdx.x >> 6;
    int node = blockIdx.x * 8 + wave * 2 + (lane >> 5);
    int l = lane & 31;
    float s0 = 0.f, s1 = 0.f;
    if (node < n) {
        float4 v = ((const float4*)(agg1 + (size_t)node * HID_C))[l];
        v.x = fmaxf(v.x, 0.f); v.y = fmaxf(v.y, 0.f);
        v.z = fmaxf(v.z, 0.f); v.w = fmaxf(v.w, 0.f);
        const float2* w2 = (const float2*)W2;
        float2 w0 = w2[l * 4 + 0], w1 = w2[l * 4 + 1];
        float2 wq = w2[l * 4 + 2], w3 = w2[l * 4 + 3];
        s0 = v.x * w0.x + v.y * w1.x + v.z * wq.x + v.w * w3.x;
        s1 = v.x * w0.y + v.y * w1.y + v.z * wq.y + v.w * w3.y;
    }
#pragma unroll
    for (int d = 16; d > 0; d >>= 1) {
        s0 += __shfl_down(s0, d, 32);
        s1 += __shfl_down(s1, d, 32);
    }
    if (node < n && l == 0)
        ((float2*)h2)[node] = make_float2(s0, s1);
}

// ---- layer-2 aggregation: wave/node, lanes over edges ----------------------
__global__ __launch_bounds__(256) void k_agg2(const int* __restrict__ rowptr,
                                              const int2* __restrict__ edata,
                                              const float* __restrict__ h2,
                                              const float* __restrict__ dinv,
                                              const float* __restrict__ b2,
                                              float* __restrict__ out, int n) {
    int wid  = (blockIdx.x * 256 + threadIdx.x) >> 6;
    int lane = threadIdx.x & 63;
    if (wid >= n) return;
    int beg = rowptr[wid], end = rowptr[wid + 1];
    float sx = 0.f, sy = 0.f;
    for (int j = beg + lane; j < end; j += 64) {
        int es; float nm;
        ntld_edge(&edata[j], es, nm);
        float2 v = ((const float2*)h2)[es];
        sx = fmaf(nm, v.x, sx);
        sy = fmaf(nm, v.y, sy);
    }
#pragma unroll
    for (int d = 32; d > 0; d >>= 1) {
        sx += __shfl_xor(sx, d);
        sy += __shfl_xor(sy, d);
    }
    if (lane == 0) {
        float di = dinv[wid]; float sc = di * di;
        float2 hv = ((const float2*)h2)[wid];
        ((float2*)out)[wid] = make_float2(b2[0] + sc * hv.x + di * sx,
                                          b2[1] + sc * hv.y + di * sy);
    }
}

extern "C" void kernel_launch(void* const* d_in, const int* in_sizes, int n_in,
                              void* d_out, int out_size, void* d_ws, size_t ws_size,
                              hipStream_t stream) {
    const float* x  = (const float*)d_in[0];
    const int*   ei = (const int*)d_in[1];   // [2,E] int32
    const float* ew = (const float*)d_in[2];
    const float* W1 = (const float*)d_in[3];
    const float* b1 = (const float*)d_in[4];
    const float* W2 = (const float*)d_in[5];
    const float* b2 = (const float*)d_in[6];
    float* out = (float*)d_out;

    int N = in_sizes[0] / IN_C;
    int E = in_sizes[2];
    int K = (N + NB - 1) >> BSH;             // buckets (3125)
    int W = (E + CH - 1) / CH;               // pass-1 workgroups (196)
    int KW = K * W;

    char* ws = (char*)d_ws;
    float* dinv   = (float*)ws; ws += (size_t)N * 4;
    int*   rowptr = (int*)ws;   ws += (size_t)(N + 1) * 4 + 4;
    int*   gcnt   = (int*)ws;   ws += (size_t)KW * 4;
    int*   bsum   = (int*)ws;   ws += 1024;
    int2*  ebuf   = (int2*)ws;  ws += (size_t)E * 8;
    int2*  edata  = (int2*)ws;  ws += (size_t)E * 8;
    unsigned short* w1t = (unsigned short*)ws; ws += (size_t)HID_C * IN_C * 2;
    unsigned short* h1b = (unsigned short*)ws; ws += (size_t)N * HID_C * 2;
    float* agg1   = (float*)ws; ws += (size_t)N * HID_C * 4;
    float* h2     = (float*)ws; ws += (size_t)N * OUT_C * 4;

    int nb_e  = (E + 255) / 256;
    int nb_s4 = (KW + 4095) / 4096;
    int nb_sc = (KW + 255) / 256;
    int nb_w  = (N * 64 + 255) / 256;
    size_t lds_k = (size_t)K * 4;            // 12.5 KB dynamic LDS

    k_wT    <<<(HID_C * IN_C + 255) / 256, 256, 0, stream>>>(W1, w1t);
    k_count <<<W, 256, lds_k, stream>>>(ei, gcnt, E, K, W);
    k_scanA4<<<nb_s4, 256, 0, stream>>>(gcnt, gcnt, bsum, KW);
    k_scanB <<<1, 256, 0, stream>>>(bsum, nb_s4);
    k_scanC4<<<nb_sc, 256, 0, stream>>>(gcnt, bsum, KW);
    k_place <<<W, 256, lds_k, stream>>>(ei, ew, gcnt, ebuf, E, K, W);
    k_bucket<<<K, 256, 0, stream>>>(ebuf, gcnt, edata, rowptr, dinv, W, K, E, N);
    k_scale <<<nb_e, 256, 0, stream>>>(edata, dinv, E);
    k_gemm1 <<<(N + 63) / 64, 256, 0, stream>>>(x, w1t, h1b, N);
    k_agg1  <<<nb_w, 256, 0, stream>>>(rowptr, edata, h1b, dinv, b1, agg1, N);
    k_gemm2 <<<(N + 7) / 8, 256, 0, stream>>>(agg1, W2, h2, N);
    k_agg2  <<<nb_w, 256, 0, stream>>>(rowptr, edata, h2, dinv, b2, out, N);
}

// Round 9
// 532.213 us; speedup vs baseline: 11.8419x; 1.0769x over previous
//
#include <hip/hip_runtime.h>

#define IN_C  256
#define HID_C 128
#define OUT_C 2
#define BSH   5                    // nodes per bucket = 32
#define NB    32
#define BCAP  2048                 // k_bucket LDS edge capacity

typedef __attribute__((ext_vector_type(8))) short short8;
typedef __attribute__((ext_vector_type(4))) float float4v;

__device__ __forceinline__ unsigned short f2bf(float f) {   // RNE float->bf16
    unsigned u = __float_as_uint(f);
    unsigned r = 0x7fffu + ((u >> 16) & 1u);
    return (unsigned short)((u + r) >> 16);
}
__device__ __forceinline__ unsigned pk2(float a, float b) {
    return (unsigned)f2bf(a) | ((unsigned)f2bf(b) << 16);
}

// ---- W1^T bf16 precompute --------------------------------------------------
__global__ void k_wT(const float* __restrict__ W1, unsigned short* __restrict__ w1t) {
    int i = blockIdx.x * 256 + threadIdx.x;     // i = c*256 + k (write-coalesced)
    if (i >= HID_C * IN_C) return;
    int c = i >> 8, k = i & 255;
    w1t[i] = f2bf(W1[(size_t)k * HID_C + c]);
}

// ---- pass 1a: per-wg bucket histogram -> gcnt[b*W + w] ---------------------
__global__ __launch_bounds__(256) void k_count(const int* __restrict__ ei,
                                               int* __restrict__ gcnt,
                                               int E, int K, int W, int CHv) {
    extern __shared__ int lh[];                // K ints
    int w = blockIdx.x, t = threadIdx.x;
    for (int b = t; b < K; b += 256) lh[b] = 0;
    __syncthreads();
    int j0 = w * CHv;
    int j1 = min(j0 + CHv, E);
    for (int j = j0 + t; j < j1; j += 256)
        atomicAdd(&lh[ei[E + j] >> BSH], 1);
    __syncthreads();
    for (int b = t; b < K; b += 256) gcnt[(size_t)b * W + w] = lh[b];
}

// ---- scan: 4096 elems/block ------------------------------------------------
__global__ __launch_bounds__(256) void k_scanA4(const int* __restrict__ cnt,
                                                int* __restrict__ excl,
                                                int* __restrict__ bsum, int n) {
    __shared__ int ss[256];
    int t = threadIdx.x;
    int base = blockIdx.x * 4096 + t * 16;
    int v[16]; int s = 0;
#pragma unroll
    for (int q = 0; q < 16; q++) { v[q] = (base + q < n) ? cnt[base + q] : 0; s += v[q]; }
    ss[t] = s;
    __syncthreads();
    for (int d = 1; d < 256; d <<= 1) {
        int x = (t >= d) ? ss[t - d] : 0;
        __syncthreads();
        ss[t] += x;
        __syncthreads();
    }
    int pre = (t == 0) ? 0 : ss[t - 1];
    if (t == 255) bsum[blockIdx.x] = ss[255];
    int run = pre;
#pragma unroll
    for (int q = 0; q < 16; q++) { if (base + q < n) excl[base + q] = run; run += v[q]; }
}

__global__ __launch_bounds__(256) void k_scanB(int* __restrict__ bsum, int nb) {
    __shared__ int ss[256];
    int t = threadIdx.x;
    int v = (t < nb) ? bsum[t] : 0;
    ss[t] = v;
    __syncthreads();
    for (int d = 1; d < 256; d <<= 1) {
        int x = (t >= d) ? ss[t - d] : 0;
        __syncthreads();
        ss[t] += x;
        __syncthreads();
    }
    if (t < nb) bsum[t] = ss[t] - v;   // exclusive
}

__global__ void k_scanC4(int* __restrict__ gpos, const int* __restrict__ bsum, int n) {
    int i = blockIdx.x * 256 + threadIdx.x;
    if (i < n) gpos[i] += bsum[i >> 12];
}

// ---- pass 1c: place edges into ebuf, bucket-grouped ------------------------
// ebuf entry: {src | ldst<<17, w}   (src < 2^17, ldst < 32)
__global__ __launch_bounds__(256) void k_place(const int* __restrict__ ei,
                                               const float* __restrict__ w,
                                               const int* __restrict__ gpos,
                                               int2* __restrict__ ebuf,
                                               int E, int K, int W, int CHv) {
    extern __shared__ int lc[];                // K cursors
    int wg = blockIdx.x, t = threadIdx.x;
    for (int b = t; b < K; b += 256) lc[b] = gpos[(size_t)b * W + wg];
    __syncthreads();
    int j0 = wg * CHv;
    int j1 = min(j0 + CHv, E);
    for (int j = j0 + t; j < j1; j += 256) {
        int s = ei[j], d = ei[E + j];
        float wv = w[j];
        int pos = atomicAdd(&lc[d >> BSH], 1);
        ebuf[pos] = make_int2(s | ((d & (NB - 1)) << 17), __float_as_int(wv));
    }
}

// ---- pass 2: per-bucket fine CSR + dinv, single ebuf read, LDS sort --------
__global__ __launch_bounds__(256) void k_bucket(const int2* __restrict__ ebuf,
                                                const int* __restrict__ gpos,
                                                int2* __restrict__ edata,
                                                int* __restrict__ rowptr,
                                                float* __restrict__ dinv,
                                                int W, int K, int E, int N) {
    __shared__ int2 le[BCAP], ls[BCAP];
    __shared__ int lh[NB], lex[NB], lc[NB];
    int b = blockIdx.x, t = threadIdx.x;
    int base = gpos[(size_t)b * W];
    int next = (b + 1 < K) ? gpos[(size_t)(b + 1) * W] : E;
    int cnt = next - base;
    if (t < NB) lh[t] = 0;
    __syncthreads();
    if (cnt <= BCAP) {
        for (int j = t; j < cnt; j += 256) {
            int2 e = ebuf[base + j];
            le[j] = e;
            atomicAdd(&lh[(e.x >> 17) & (NB - 1)], 1);
        }
        __syncthreads();
        if (t == 0) {
            int run = 0;
            for (int i = 0; i < NB; i++) { lex[i] = run; lc[i] = run; run += lh[i]; }
        }
        __syncthreads();
        for (int j = t; j < cnt; j += 256) {
            int2 e = le[j];
            int pos = atomicAdd(&lc[(e.x >> 17) & (NB - 1)], 1);
            ls[pos] = make_int2(e.x & 0x1FFFF, e.y);
        }
        __syncthreads();
        for (int j = t; j < cnt; j += 256) edata[base + j] = ls[j];   // coalesced
        if (t < NB) {
            int node = b * NB + t;
            if (node < N) {
                rowptr[node] = base + lex[t];
                float s = 1.0f;                      // self-loop weight
                int rb = lex[t], re = rb + lh[t];
                for (int j = rb; j < re; j++) s += __int_as_float(ls[j].y);
                dinv[node] = s > 0.f ? rsqrtf(s) : 0.f;
            }
        }
    } else {                                         // fallback (never at E/N=32)
        for (int j = base + t; j < next; j += 256)
            atomicAdd(&lh[(ebuf[j].x >> 17) & (NB - 1)], 1);
        __syncthreads();
        if (t == 0) {
            int run = 0;
            for (int i = 0; i < NB; i++) { lex[i] = run; lc[i] = run; run += lh[i]; }
        }
        __syncthreads();
        for (int j = base + t; j < next; j += 256) {
            int2 e = ebuf[j];
            int pos = base + atomicAdd(&lc[(e.x >> 17) & (NB - 1)], 1);
            edata[pos] = make_int2(e.x & 0x1FFFF, e.y);
        }
        __syncthreads();
        if (t < NB) {
            int node = b * NB + t;
            if (node < N) {
                int rb = base + lex[t], re = rb + lh[t];
                rowptr[node] = rb;
                float s = 1.0f;
                for (int j = rb; j < re; j++) s += __int_as_float(edata[j].y);
                dinv[node] = s > 0.f ? rsqrtf(s) : 0.f;
            }
        }
    }
    if (b == K - 1 && t == 0) rowptr[N] = E;
}

// ---- scale edge weights by dinv[src] --------------------------------------
__global__ void k_scale(int2* __restrict__ edata, const float* __restrict__ dinv, int E) {
    int i = blockIdx.x * 256 + threadIdx.x;
    if (i >= E) return;
    int2 e = edata[i];
    e.y = __float_as_int(__int_as_float(e.y) * dinv[e.x]);
    edata[i] = e;
}

// ---- GEMM1 (MFMA bf16): h1b[N,128] = x[N,256] @ W1 -------------------------
#define XS_LD 36
#define WT_LD 260
__global__ __launch_bounds__(256) void k_gemm1(const float* __restrict__ x,
                                               const unsigned short* __restrict__ w1t,
                                               unsigned short* __restrict__ h1b, int n) {
    __shared__ __align__(16) unsigned short wt[HID_C * WT_LD];
    __shared__ __align__(16) unsigned short xs[64 * XS_LD];
    int tid  = threadIdx.x;
    int row0 = blockIdx.x * 64;
    for (int it = 0; it < 16; it++) {
        int idx = it * 256 + tid;
        int c = idx >> 5, kc = idx & 31;
        uint4 v = *(const uint4*)(w1t + (size_t)c * IN_C + kc * 8);
        uint2* dst = (uint2*)(wt + c * WT_LD + kc * 8);
        dst[0] = make_uint2(v.x, v.y);
        dst[1] = make_uint2(v.z, v.w);
    }
    int wv = tid >> 6, ln = tid & 63;
    int m = ln & 15, quad = ln >> 4;
    float4v acc[8];
#pragma unroll
    for (int ct = 0; ct < 8; ct++) acc[ct] = (float4v){0.f, 0.f, 0.f, 0.f};

    for (int k0 = 0; k0 < IN_C; k0 += 32) {
        __syncthreads();
        {
            int r = tid >> 2, s4 = tid & 3;
            int gr = row0 + r; if (gr >= n) gr = n - 1;
            const float4* px = (const float4*)(x + (size_t)gr * IN_C + k0 + s4 * 8);
            float4 a = px[0], bq = px[1];
            uint2* d = (uint2*)(xs + r * XS_LD + s4 * 8);
            d[0] = make_uint2(pk2(a.x, a.y), pk2(a.z, a.w));
            d[1] = make_uint2(pk2(bq.x, bq.y), pk2(bq.z, bq.w));
        }
        __syncthreads();
        union { uint2 u[2]; short8 v; } af;
        const uint2* pa = (const uint2*)(xs + (wv * 16 + m) * XS_LD + quad * 8);
        af.u[0] = pa[0]; af.u[1] = pa[1];
#pragma unroll
        for (int ct = 0; ct < 8; ct++) {
            union { uint2 u[2]; short8 v; } bf;
            const uint2* pb = (const uint2*)(wt + (ct * 16 + m) * WT_LD + k0 + quad * 8);
            bf.u[0] = pb[0]; bf.u[1] = pb[1];
            acc[ct] = __builtin_amdgcn_mfma_f32_16x16x32_bf16(af.v, bf.v, acc[ct], 0, 0, 0);
        }
    }
    __syncthreads();
    unsigned short* ot = wt;
#pragma unroll
    for (int ct = 0; ct < 8; ct++)
#pragma unroll
        for (int r = 0; r < 4; r++)
            ot[(wv * 16 + quad * 4 + r) * 136 + ct * 16 + m] = f2bf(acc[ct][r]);
    __syncthreads();
#pragma unroll
    for (int p = 0; p < 4; p++) {
        int idx = p * 256 + tid;
        int r = idx >> 4, c8 = idx & 15;
        if (row0 + r < n)
            *(uint4*)(h1b + (size_t)(row0 + r) * HID_C + c8 * 8) =
                *(const uint4*)(ot + r * 136 + c8 * 8);
    }
}

// ---- layer-1 aggregation + fused gemm2: h2[n] = relu(agg_row) @ W2 ---------
__global__ __launch_bounds__(256) void k_agg1(const int* __restrict__ rowptr,
                                              const int2* __restrict__ edata,
                                              const unsigned short* __restrict__ h1b,
                                              const float* __restrict__ dinv,
                                              const float* __restrict__ b1,
                                              const float* __restrict__ W2,
                                              float* __restrict__ h2, int n) {
    int wid  = (blockIdx.x * 256 + threadIdx.x) >> 6;
    int lane = threadIdx.x & 63;
    if (wid >= n) return;
    int beg = rowptr[wid], end = rowptr[wid + 1];
    float ax = 0.f, ay = 0.f;
    int j = beg;
    for (; j + 16 <= end; j += 16) {
        int2 e[16];
        unsigned p[16];
#pragma unroll
        for (int q = 0; q < 16; q++) e[q] = edata[j + q];
#pragma unroll
        for (int q = 0; q < 16; q++)
            p[q] = *((const unsigned*)(h1b + (size_t)e[q].x * HID_C) + lane);
#pragma unroll
        for (int q = 0; q < 16; q++) {
            float nm = __int_as_float(e[q].y);
            ax = fmaf(nm, __uint_as_float(p[q] << 16), ax);
            ay = fmaf(nm, __uint_as_float(p[q] & 0xffff0000u), ay);
        }
    }
    for (; j + 4 <= end; j += 4) {
        int2 e[4];
        unsigned p[4];
#pragma unroll
        for (int q = 0; q < 4; q++) e[q] = edata[j + q];
#pragma unroll
        for (int q = 0; q < 4; q++)
            p[q] = *((const unsigned*)(h1b + (size_t)e[q].x * HID_C) + lane);
#pragma unroll
        for (int q = 0; q < 4; q++) {
            float nm = __int_as_float(e[q].y);
            ax = fmaf(nm, __uint_as_float(p[q] << 16), ax);
            ay = fmaf(nm, __uint_as_float(p[q] & 0xffff0000u), ay);
        }
    }
    for (; j < end; j++) {
        int2 e0 = edata[j];
        unsigned p0 = *((const unsigned*)(h1b + (size_t)e0.x * HID_C) + lane);
        float nm = __int_as_float(e0.y);
        ax = fmaf(nm, __uint_as_float(p0 << 16), ax);
        ay = fmaf(nm, __uint_as_float(p0 & 0xffff0000u), ay);
    }
    // epilogue: agg row (2 ch/lane) -> relu -> dot W2 -> wave-reduce -> h2
    float di = dinv[wid]; float sc = di * di;
    unsigned ps = *((const unsigned*)(h1b + (size_t)wid * HID_C) + lane);
    float2 bv = ((const float2*)b1)[lane];
    float ox = bv.x + sc * __uint_as_float(ps << 16)         + di * ax;
    float oy = bv.y + sc * __uint_as_float(ps & 0xffff0000u) + di * ay;
    ox = fmaxf(ox, 0.f);
    oy = fmaxf(oy, 0.f);
    float4 w4 = *((const float4*)(W2 + 4 * lane));   // W2[2l][0],W2[2l][1],W2[2l+1][0],W2[2l+1][1]
    float s0 = ox * w4.x + oy * w4.z;
    float s1 = ox * w4.y + oy * w4.w;
#pragma unroll
    for (int d = 32; d > 0; d >>= 1) {
        s0 += __shfl_xor(s0, d);
        s1 += __shfl_xor(s1, d);
    }
    if (lane == 0)
        ((float2*)h2)[wid] = make_float2(s0, s1);
}

// ---- layer-2 aggregation: wave/node, lanes over edges ----------------------
__global__ __launch_bounds__(256) void k_agg2(const int* __restrict__ rowptr,
                                              const int2* __restrict__ edata,
                                              const float* __restrict__ h2,
                                              const float* __restrict__ dinv,
                                              const float* __restrict__ b2,
                                              float* __restrict__ out, int n) {
    int wid  = (blockIdx.x * 256 + threadIdx.x) >> 6;
    int lane = threadIdx.x & 63;
    if (wid >= n) return;
    int beg = rowptr[wid], end = rowptr[wid + 1];
    float sx = 0.f, sy = 0.f;
    for (int j = beg + lane; j < end; j += 64) {
        int2 ed = edata[j];
        float nm = __int_as_float(ed.y);
        float2 v = ((const float2*)h2)[ed.x];
        sx = fmaf(nm, v.x, sx);
        sy = fmaf(nm, v.y, sy);
    }
#pragma unroll
    for (int d = 32; d > 0; d >>= 1) {
        sx += __shfl_xor(sx, d);
        sy += __shfl_xor(sy, d);
    }
    if (lane == 0) {
        float di = dinv[wid]; float sc = di * di;
        float2 hv = ((const float2*)h2)[wid];
        ((float2*)out)[wid] = make_float2(b2[0] + sc * hv.x + di * sx,
                                          b2[1] + sc * hv.y + di * sy);
    }
}

extern "C" void kernel_launch(void* const* d_in, const int* in_sizes, int n_in,
                              void* d_out, int out_size, void* d_ws, size_t ws_size,
                              hipStream_t stream) {
    const float* x  = (const float*)d_in[0];
    const int*   ei = (const int*)d_in[1];   // [2,E] int32
    const float* ew = (const float*)d_in[2];
    const float* W1 = (const float*)d_in[3];
    const float* b1 = (const float*)d_in[4];
    const float* W2 = (const float*)d_in[5];
    const float* b2 = (const float*)d_in[6];
    float* out = (float*)d_out;

    int N = in_sizes[0] / IN_C;
    int E = in_sizes[2];
    int K = (N + NB - 1) >> BSH;             // buckets (3125)
    int W = 256;                             // pass-1 workgroups = CU count
    int CHv = (E + W - 1) / W;               // edges per workgroup
    int KW = K * W;

    char* ws = (char*)d_ws;
    float* dinv   = (float*)ws; ws += (size_t)N * 4;
    int*   rowptr = (int*)ws;   ws += (size_t)(N + 1) * 4 + 4;
    int*   gcnt   = (int*)ws;   ws += (size_t)KW * 4;
    int*   bsum   = (int*)ws;   ws += 1024;
    int2*  ebuf   = (int2*)ws;  ws += (size_t)E * 8;
    int2*  edata  = (int2*)ws;  ws += (size_t)E * 8;
    unsigned short* w1t = (unsigned short*)ws; ws += (size_t)HID_C * IN_C * 2;
    unsigned short* h1b = (unsigned short*)ws; ws += (size_t)N * HID_C * 2;
    float* h2     = (float*)ws; ws += (size_t)N * OUT_C * 4;

    int nb_e  = (E + 255) / 256;
    int nb_s4 = (KW + 4095) / 4096;
    int nb_sc = (KW + 255) / 256;
    int nb_w  = (N * 64 + 255) / 256;
    size_t lds_k = (size_t)K * 4;            // 12.5 KB dynamic LDS

    k_wT    <<<(HID_C * IN_C + 255) / 256, 256, 0, stream>>>(W1, w1t);
    k_count <<<W, 256, lds_k, stream>>>(ei, gcnt, E, K, W, CHv);
    k_scanA4<<<nb_s4, 256, 0, stream>>>(gcnt, gcnt, bsum, KW);
    k_scanB <<<1, 256, 0, stream>>>(bsum, nb_s4);
    k_scanC4<<<nb_sc, 256, 0, stream>>>(gcnt, bsum, KW);
    k_place <<<W, 256, lds_k, stream>>>(ei, ew, gcnt, ebuf, E, K, W, CHv);
    k_bucket<<<K, 256, 0, stream>>>(ebuf, gcnt, edata, rowptr, dinv, W, K, E, N);
    k_scale <<<nb_e, 256, 0, stream>>>(edata, dinv, E);
    k_gemm1 <<<(N + 63) / 64, 256, 0, stream>>>(x, w1t, h1b, N);
    k_agg1  <<<nb_w, 256, 0, stream>>>(rowptr, edata, h1b, dinv, b1, W2, h2, N);
    k_agg2  <<<nb_w, 256, 0, stream>>>(rowptr, edata, h2, dinv, b2, out, N);
}

// Round 10
// 501.717 us; speedup vs baseline: 12.5617x; 1.0608x over previous
//
#include <hip/hip_runtime.h>
#include <hip/hip_fp16.h>

#define IN_C  256
#define HID_C 128
#define OUT_C 2
#define BSH   7                    // nodes per bucket = 128
#define NB    128
#define BCAP  6144                 // k_bucket LDS edge capacity (mean 4096)

typedef __attribute__((ext_vector_type(8))) short short8;
typedef __attribute__((ext_vector_type(4))) float float4v;

__device__ __forceinline__ unsigned short f2bf(float f) {   // RNE float->bf16
    unsigned u = __float_as_uint(f);
    unsigned r = 0x7fffu + ((u >> 16) & 1u);
    return (unsigned short)((u + r) >> 16);
}
__device__ __forceinline__ unsigned pk2(float a, float b) {
    return (unsigned)f2bf(a) | ((unsigned)f2bf(b) << 16);
}
// edge record: bits[16:0]=src, bits[31:17]=fp16(norm) without sign (norm>=0)
__device__ __forceinline__ unsigned enc_edge(int src, float w) {
    unsigned h = (unsigned)(__half_as_ushort(__float2half(w)) & 0x7FFF);
    return (h << 17) | (unsigned)src;
}
__device__ __forceinline__ void dec_edge(unsigned rec, int& s, float& w) {
    s = (int)(rec & 0x1FFFFu);
    __half hh;
    *(unsigned short*)&hh = (unsigned short)(rec >> 17);
    w = __half2float(hh);
}

// ---- W1^T bf16 precompute --------------------------------------------------
__global__ void k_wT(const float* __restrict__ W1, unsigned short* __restrict__ w1t) {
    int i = blockIdx.x * 256 + threadIdx.x;     // i = c*256 + k (write-coalesced)
    if (i >= HID_C * IN_C) return;
    int c = i >> 8, k = i & 255;
    w1t[i] = f2bf(W1[(size_t)k * HID_C + c]);
}

// ---- pass 1a: per-wg bucket histogram -> gcnt[b*W + w] ---------------------
__global__ __launch_bounds__(256) void k_count(const int* __restrict__ ei,
                                               int* __restrict__ gcnt,
                                               int E, int K, int W, int CHv) {
    extern __shared__ int lh[];                // K ints
    int w = blockIdx.x, t = threadIdx.x;
    for (int b = t; b < K; b += 256) lh[b] = 0;
    __syncthreads();
    int j0 = w * CHv;
    int j1 = min(j0 + CHv, E);
    for (int j = j0 + t; j < j1; j += 256)
        atomicAdd(&lh[ei[E + j] >> BSH], 1);
    __syncthreads();
    for (int b = t; b < K; b += 256) gcnt[(size_t)b * W + w] = lh[b];
}

// ---- scan: 4096 elems/block ------------------------------------------------
__global__ __launch_bounds__(256) void k_scanA4(const int* __restrict__ cnt,
                                                int* __restrict__ excl,
                                                int* __restrict__ bsum, int n) {
    __shared__ int ss[256];
    int t = threadIdx.x;
    int base = blockIdx.x * 4096 + t * 16;
    int v[16]; int s = 0;
#pragma unroll
    for (int q = 0; q < 16; q++) { v[q] = (base + q < n) ? cnt[base + q] : 0; s += v[q]; }
    ss[t] = s;
    __syncthreads();
    for (int d = 1; d < 256; d <<= 1) {
        int x = (t >= d) ? ss[t - d] : 0;
        __syncthreads();
        ss[t] += x;
        __syncthreads();
    }
    int pre = (t == 0) ? 0 : ss[t - 1];
    if (t == 255) bsum[blockIdx.x] = ss[255];
    int run = pre;
#pragma unroll
    for (int q = 0; q < 16; q++) { if (base + q < n) excl[base + q] = run; run += v[q]; }
}

__global__ __launch_bounds__(256) void k_scanB(int* __restrict__ bsum, int nb) {
    __shared__ int ss[256];
    int t = threadIdx.x;
    int v = (t < nb) ? bsum[t] : 0;
    ss[t] = v;
    __syncthreads();
    for (int d = 1; d < 256; d <<= 1) {
        int x = (t >= d) ? ss[t - d] : 0;
        __syncthreads();
        ss[t] += x;
        __syncthreads();
    }
    if (t < nb) bsum[t] = ss[t] - v;   // exclusive
}

__global__ void k_scanC4(int* __restrict__ gpos, const int* __restrict__ bsum, int n) {
    int i = blockIdx.x * 256 + threadIdx.x;
    if (i < n) gpos[i] += bsum[i >> 12];
}

// ---- pass 1c: place edges into ebuf, bucket-grouped ------------------------
// ebuf entry: {src | ldst<<17, w_f32}   (src < 2^17, ldst < 128)
__global__ __launch_bounds__(256) void k_place(const int* __restrict__ ei,
                                               const float* __restrict__ w,
                                               const int* __restrict__ gpos,
                                               int2* __restrict__ ebuf,
                                               int E, int K, int W, int CHv) {
    extern __shared__ int lc[];                // K cursors
    int wg = blockIdx.x, t = threadIdx.x;
    for (int b = t; b < K; b += 256) lc[b] = gpos[(size_t)b * W + wg];
    __syncthreads();
    int j0 = wg * CHv;
    int j1 = min(j0 + CHv, E);
    for (int j = j0 + t; j < j1; j += 256) {
        int s = ei[j], d = ei[E + j];
        float wv = w[j];
        int pos = atomicAdd(&lc[d >> BSH], 1);
        ebuf[pos] = make_int2(s | ((d & (NB - 1)) << 17), __float_as_int(wv));
    }
}

// ---- pass 2: per-bucket fine CSR + dinv; packed 4B edata -------------------
__global__ __launch_bounds__(256) void k_bucket(const int2* __restrict__ ebuf,
                                                const int* __restrict__ gpos,
                                                unsigned* __restrict__ epack,
                                                int* __restrict__ rowptr,
                                                float* __restrict__ dinv,
                                                int W, int K, int E, int N) {
    __shared__ int2 ls[BCAP];
    __shared__ int lh[NB], lex[NB], lc[NB];
    int b = blockIdx.x, t = threadIdx.x;
    int base = gpos[(size_t)b * W];
    int next = (b + 1 < K) ? gpos[(size_t)(b + 1) * W] : E;
    int cnt = next - base;
    for (int i = t; i < NB; i += 256) lh[i] = 0;
    __syncthreads();
    if (cnt <= BCAP) {
        for (int j = t; j < cnt; j += 256)                     // pass A: hist
            atomicAdd(&lh[(ebuf[base + j].x >> 17) & (NB - 1)], 1);
        __syncthreads();
        if (t == 0) {
            int run = 0;
            for (int i = 0; i < NB; i++) { lex[i] = run; lc[i] = run; run += lh[i]; }
        }
        __syncthreads();
        for (int j = t; j < cnt; j += 256) {                   // pass B: LDS sort
            int2 e = ebuf[base + j];
            int pos = atomicAdd(&lc[(e.x >> 17) & (NB - 1)], 1);
            ls[pos] = make_int2(e.x & 0x1FFFF, e.y);
        }
        __syncthreads();
        for (int j = t; j < cnt; j += 256) {                   // coalesced 4B out
            int2 e = ls[j];
            epack[base + j] = enc_edge(e.x, __int_as_float(e.y));
        }
        for (int r = t; r < NB; r += 256) {
            int node = b * NB + r;
            if (node < N) {
                rowptr[node] = base + lex[r];
                float s = 1.0f;                                // self-loop weight
                int rb = lex[r], re = rb + lh[r];
                for (int j = rb; j < re; j++) s += __int_as_float(ls[j].y);
                dinv[node] = s > 0.f ? rsqrtf(s) : 0.f;
            }
        }
    } else {                                                   // fallback (overflow)
        for (int j = base + t; j < next; j += 256)
            atomicAdd(&lh[(ebuf[j].x >> 17) & (NB - 1)], 1);
        __syncthreads();
        if (t == 0) {
            int run = 0;
            for (int i = 0; i < NB; i++) { lex[i] = run; lc[i] = run; run += lh[i]; }
        }
        __syncthreads();
        for (int j = base + t; j < next; j += 256) {
            int2 e = ebuf[j];
            int pos = base + atomicAdd(&lc[(e.x >> 17) & (NB - 1)], 1);
            epack[pos] = enc_edge(e.x & 0x1FFFF, __int_as_float(e.y));
        }
        __syncthreads();
        for (int r = t; r < NB; r += 256) {
            int node = b * NB + r;
            if (node < N) {
                int rb = base + lex[r], re = rb + lh[r];
                rowptr[node] = rb;
                float s = 1.0f;
                for (int j = rb; j < re; j++) {
                    int ss; float wv;
                    dec_edge(epack[j], ss, wv);
                    s += wv;
                }
                dinv[node] = s > 0.f ? rsqrtf(s) : 0.f;
            }
        }
    }
    if (b == K - 1 && t == 0) rowptr[N] = E;
}

// ---- scale packed edge weights by dinv[src] --------------------------------
__global__ void k_scale(unsigned* __restrict__ epack, const float* __restrict__ dinv, int E) {
    int i = blockIdx.x * 256 + threadIdx.x;
    if (i >= E) return;
    unsigned rec = epack[i];
    int src; float wv;
    dec_edge(rec, src, wv);
    epack[i] = enc_edge(src, wv * dinv[src]);
}

// ---- GEMM1 (MFMA bf16): h1b[N,128] = x[N,256] @ W1 -------------------------
#define XS_LD 36
#define WT_LD 260
__global__ __launch_bounds__(256) void k_gemm1(const float* __restrict__ x,
                                               const unsigned short* __restrict__ w1t,
                                               unsigned short* __restrict__ h1b, int n) {
    __shared__ __align__(16) unsigned short wt[HID_C * WT_LD];
    __shared__ __align__(16) unsigned short xs[64 * XS_LD];
    int tid  = threadIdx.x;
    int row0 = blockIdx.x * 64;
    for (int it = 0; it < 16; it++) {
        int idx = it * 256 + tid;
        int c = idx >> 5, kc = idx & 31;
        uint4 v = *(const uint4*)(w1t + (size_t)c * IN_C + kc * 8);
        uint2* dst = (uint2*)(wt + c * WT_LD + kc * 8);
        dst[0] = make_uint2(v.x, v.y);
        dst[1] = make_uint2(v.z, v.w);
    }
    int wv = tid >> 6, ln = tid & 63;
    int m = ln & 15, quad = ln >> 4;
    float4v acc[8];
#pragma unroll
    for (int ct = 0; ct < 8; ct++) acc[ct] = (float4v){0.f, 0.f, 0.f, 0.f};

    for (int k0 = 0; k0 < IN_C; k0 += 32) {
        __syncthreads();
        {
            int r = tid >> 2, s4 = tid & 3;
            int gr = row0 + r; if (gr >= n) gr = n - 1;
            const float4* px = (const float4*)(x + (size_t)gr * IN_C + k0 + s4 * 8);
            float4 a = px[0], bq = px[1];
            uint2* d = (uint2*)(xs + r * XS_LD + s4 * 8);
            d[0] = make_uint2(pk2(a.x, a.y), pk2(a.z, a.w));
            d[1] = make_uint2(pk2(bq.x, bq.y), pk2(bq.z, bq.w));
        }
        __syncthreads();
        union { uint2 u[2]; short8 v; } af;
        const uint2* pa = (const uint2*)(xs + (wv * 16 + m) * XS_LD + quad * 8);
        af.u[0] = pa[0]; af.u[1] = pa[1];
#pragma unroll
        for (int ct = 0; ct < 8; ct++) {
            union { uint2 u[2]; short8 v; } bf;
            const uint2* pb = (const uint2*)(wt + (ct * 16 + m) * WT_LD + k0 + quad * 8);
            bf.u[0] = pb[0]; bf.u[1] = pb[1];
            acc[ct] = __builtin_amdgcn_mfma_f32_16x16x32_bf16(af.v, bf.v, acc[ct], 0, 0, 0);
        }
    }
    __syncthreads();
    unsigned short* ot = wt;
#pragma unroll
    for (int ct = 0; ct < 8; ct++)
#pragma unroll
        for (int r = 0; r < 4; r++)
            ot[(wv * 16 + quad * 4 + r) * 136 + ct * 16 + m] = f2bf(acc[ct][r]);
    __syncthreads();
#pragma unroll
    for (int p = 0; p < 4; p++) {
        int idx = p * 256 + tid;
        int r = idx >> 4, c8 = idx & 15;
        if (row0 + r < n)
            *(uint4*)(h1b + (size_t)(row0 + r) * HID_C + c8 * 8) =
                *(const uint4*)(ot + r * 136 + c8 * 8);
    }
}

// ---- layer-1 aggregation + fused gemm2: h2[n] = relu(agg_row) @ W2 ---------
__global__ __launch_bounds__(256) void k_agg1(const int* __restrict__ rowptr,
                                              const unsigned* __restrict__ epack,
                                              const unsigned short* __restrict__ h1b,
                                              const float* __restrict__ dinv,
                                              const float* __restrict__ b1,
                                              const float* __restrict__ W2,
                                              float* __restrict__ h2, int n) {
    int wid  = (blockIdx.x * 256 + threadIdx.x) >> 6;
    int lane = threadIdx.x & 63;
    if (wid >= n) return;
    int beg = rowptr[wid], end = rowptr[wid + 1];
    float ax = 0.f, ay = 0.f;
    int j = beg;
    for (; j + 16 <= end; j += 16) {
        int   es[16]; float ew[16];
        unsigned p[16];
#pragma unroll
        for (int q = 0; q < 16; q++) dec_edge(epack[j + q], es[q], ew[q]);
#pragma unroll
        for (int q = 0; q < 16; q++)
            p[q] = *((const unsigned*)(h1b + (size_t)es[q] * HID_C) + lane);
#pragma unroll
        for (int q = 0; q < 16; q++) {
            ax = fmaf(ew[q], __uint_as_float(p[q] << 16), ax);
            ay = fmaf(ew[q], __uint_as_float(p[q] & 0xffff0000u), ay);
        }
    }
    for (; j + 4 <= end; j += 4) {
        int   es[4]; float ew[4];
        unsigned p[4];
#pragma unroll
        for (int q = 0; q < 4; q++) dec_edge(epack[j + q], es[q], ew[q]);
#pragma unroll
        for (int q = 0; q < 4; q++)
            p[q] = *((const unsigned*)(h1b + (size_t)es[q] * HID_C) + lane);
#pragma unroll
        for (int q = 0; q < 4; q++) {
            ax = fmaf(ew[q], __uint_as_float(p[q] << 16), ax);
            ay = fmaf(ew[q], __uint_as_float(p[q] & 0xffff0000u), ay);
        }
    }
    for (; j < end; j++) {
        int es; float ewv;
        dec_edge(epack[j], es, ewv);
        unsigned p0 = *((const unsigned*)(h1b + (size_t)es * HID_C) + lane);
        ax = fmaf(ewv, __uint_as_float(p0 << 16), ax);
        ay = fmaf(ewv, __uint_as_float(p0 & 0xffff0000u), ay);
    }
    // epilogue: agg row (2 ch/lane) -> relu -> dot W2 -> wave-reduce -> h2
    float di = dinv[wid]; float sc = di * di;
    unsigned ps = *((const unsigned*)(h1b + (size_t)wid * HID_C) + lane);
    float2 bv = ((const float2*)b1)[lane];
    float ox = bv.x + sc * __uint_as_float(ps << 16)         + di * ax;
    float oy = bv.y + sc * __uint_as_float(ps & 0xffff0000u) + di * ay;
    ox = fmaxf(ox, 0.f);
    oy = fmaxf(oy, 0.f);
    float4 w4 = *((const float4*)(W2 + 4 * lane));
    float s0 = ox * w4.x + oy * w4.z;
    float s1 = ox * w4.y + oy * w4.w;
#pragma unroll
    for (int d = 32; d > 0; d >>= 1) {
        s0 += __shfl_xor(s0, d);
        s1 += __shfl_xor(s1, d);
    }
    if (lane == 0)
        ((float2*)h2)[wid] = make_float2(s0, s1);
}

// ---- layer-2 aggregation: wave/node, lanes over edges ----------------------
__global__ __launch_bounds__(256) void k_agg2(const int* __restrict__ rowptr,
                                              const unsigned* __restrict__ epack,
                                              const float* __restrict__ h2,
                                              const float* __restrict__ dinv,
                                              const float* __restrict__ b2,
                                              float* __restrict__ out, int n) {
    int wid  = (blockIdx.x * 256 + threadIdx.x) >> 6;
    int lane = threadIdx.x & 63;
    if (wid >= n) return;
    int beg = rowptr[wid], end = rowptr[wid + 1];
    float sx = 0.f, sy = 0.f;
    for (int j = beg + lane; j < end; j += 64) {
        int es; float nm;
        dec_edge(epack[j], es, nm);
        float2 v = ((const float2*)h2)[es];
        sx = fmaf(nm, v.x, sx);
        sy = fmaf(nm, v.y, sy);
    }
#pragma unroll
    for (int d = 32; d > 0; d >>= 1) {
        sx += __shfl_xor(sx, d);
        sy += __shfl_xor(sy, d);
    }
    if (lane == 0) {
        float di = dinv[wid]; float sc = di * di;
        float2 hv = ((const float2*)h2)[wid];
        ((float2*)out)[wid] = make_float2(b2[0] + sc * hv.x + di * sx,
                                          b2[1] + sc * hv.y + di * sy);
    }
}

extern "C" void kernel_launch(void* const* d_in, const int* in_sizes, int n_in,
                              void* d_out, int out_size, void* d_ws, size_t ws_size,
                              hipStream_t stream) {
    const float* x  = (const float*)d_in[0];
    const int*   ei = (const int*)d_in[1];   // [2,E] int32
    const float* ew = (const float*)d_in[2];
    const float* W1 = (const float*)d_in[3];
    const float* b1 = (const float*)d_in[4];
    const float* W2 = (const float*)d_in[5];
    const float* b2 = (const float*)d_in[6];
    float* out = (float*)d_out;

    int N = in_sizes[0] / IN_C;
    int E = in_sizes[2];
    int K = (N + NB - 1) >> BSH;             // buckets (782)
    int W = 256;                             // pass-1 workgroups = CU count
    int CHv = (E + W - 1) / W;               // edges per workgroup
    int KW = K * W;

    char* ws = (char*)d_ws;
    float* dinv   = (float*)ws; ws += (size_t)N * 4;
    int*   rowptr = (int*)ws;   ws += (size_t)(N + 1) * 4 + 4;
    int*   gcnt   = (int*)ws;   ws += (size_t)KW * 4;
    int*   bsum   = (int*)ws;   ws += 1024;
    int2*  ebuf   = (int2*)ws;  ws += (size_t)E * 8;
    unsigned* epack = (unsigned*)ws; ws += (size_t)E * 4;
    unsigned short* w1t = (unsigned short*)ws; ws += (size_t)HID_C * IN_C * 2;
    unsigned short* h1b = (unsigned short*)ws; ws += (size_t)N * HID_C * 2;
    float* h2     = (float*)ws; ws += (size_t)N * OUT_C * 4;

    int nb_e  = (E + 255) / 256;
    int nb_s4 = (KW + 4095) / 4096;
    int nb_sc = (KW + 255) / 256;
    int nb_w  = (N * 64 + 255) / 256;
    size_t lds_k = (size_t)K * 4;            // ~3.1 KB dynamic LDS

    k_wT    <<<(HID_C * IN_C + 255) / 256, 256, 0, stream>>>(W1, w1t);
    k_count <<<W, 256, lds_k, stream>>>(ei, gcnt, E, K, W, CHv);
    k_scanA4<<<nb_s4, 256, 0, stream>>>(gcnt, gcnt, bsum, KW);
    k_scanB <<<1, 256, 0, stream>>>(bsum, nb_s4);
    k_scanC4<<<nb_sc, 256, 0, stream>>>(gcnt, bsum, KW);
    k_place <<<W, 256, lds_k, stream>>>(ei, ew, gcnt, ebuf, E, K, W, CHv);
    k_bucket<<<K, 256, 0, stream>>>(ebuf, gcnt, epack, rowptr, dinv, W, K, E, N);
    k_scale <<<nb_e, 256, 0, stream>>>(epack, dinv, E);
    k_gemm1 <<<(N + 63) / 64, 256, 0, stream>>>(x, w1t, h1b, N);
    k_agg1  <<<nb_w, 256, 0, stream>>>(rowptr, epack, h1b, dinv, b1, W2, h2, N);
    k_agg2  <<<nb_w, 256, 0, stream>>>(rowptr, epack, h2, dinv, b2, out, N);
}